// Round 4
// baseline (1004.712 us; speedup 1.0000x reference)
//
#include <hip/hip_runtime.h>
#include <hip/hip_bf16.h>
#include <math.h>

// Problem constants (from reference)
constexpr int NTOT = 4608;   // N_NODES
constexpr int TC   = 3072;   // TOTAL_CATS
constexpr int MU   = 1536;   // MAX_UNIFY
constexpr int NH   = 4;      // heads
// dims: nfeat=512, nfeat_out=256, nfeat_adj=64, nhid=64, att_out=256, mlp=512

// ---------------- workspace layout (float offsets) ----------------
// adj buffer holds RAW sim (unscaled); rinv carried separately.
constexpr long OFF_ADJ  = 0;                                  // N*N raw sim
constexpr long OFF_X1   = OFF_ADJ  + (long)NTOT*NTOT;         // N*256 (pre-relu)
constexpr long OFF_NAF  = OFF_X1   + (long)NTOT*256;          // N*64
constexpr long OFF_PART = OFF_NAF  + (long)NTOT*64;           // (unused, kept for layout)
constexpr long OFF_RINV = OFF_PART + 72*64;                   // N
constexpr long OFF_WH   = OFF_RINV + NTOT;                    // 4*N*64
constexpr long OFF_F1H  = OFF_WH   + (long)4*NTOT*64;         // 4*N
constexpr long OFF_F2H  = OFF_F1H  + (long)4*NTOT;
constexpr long OFF_MXH  = OFF_F2H  + (long)4*NTOT;
constexpr long OFF_CIH  = OFF_MXH  + (long)4*NTOT;
constexpr long OFF_X2   = OFF_CIH  + (long)4*NTOT;            // N*256
constexpr long OFF_WH2  = OFF_X2   + (long)NTOT*256;          // N*256
constexpr long OFF_F1S  = OFF_WH2  + (long)NTOT*256;          // N
constexpr long OFF_F2S  = OFF_F1S  + NTOT;
constexpr long OFF_MXS  = OFF_F2S  + NTOT;
constexpr long OFF_CIS  = OFF_MXS  + NTOT;
constexpr long OFF_X3   = OFF_CIS  + NTOT;                    // 1536*256
constexpr long OFF_PMAX = OFF_X3   + (long)MU*256;            // 2*12*1536
constexpr long OFF_PSUM = OFF_PMAX + (long)2*12*MU;
constexpr long OFF_FMAX = OFF_PSUM + (long)2*12*MU;           // 2*1536
constexpr long OFF_FIS  = OFF_FMAX + (long)2*MU;

__device__ __forceinline__ float lrelu(float x) { return (x >= 0.f) ? x : 0.2f * x; }
__device__ __forceinline__ float elu(float x)   { return (x > 0.f) ? x : expm1f(x); }

// ---------------- generic tiled fp32 GEMM: C = A(NxK) @ B(KxM) [+bias] ----------------
template<bool RELU_A, bool BIAS>
__global__ __launch_bounds__(256) void gemm_rm(
    const float* __restrict__ A, const float* __restrict__ B,
    const float* __restrict__ bias, float* __restrict__ C,
    int K, int M, long strideBz, long strideCz)
{
    __shared__ float As[16][68];
    __shared__ float Bs[16][68];
    const float* Bz = B + (long)blockIdx.z * strideBz;
    float* Cz = C + (long)blockIdx.z * strideCz;
    int tid = threadIdx.x;
    int r0 = blockIdx.x * 64;
    int c0 = blockIdx.y * 64;
    int ty = tid >> 4, tx = tid & 15;
    float acc[4][4] = {};
    for (int k0 = 0; k0 < K; k0 += 16) {
        #pragma unroll
        for (int l = 0; l < 4; ++l) {
            int idx = l * 256 + tid;
            int row = idx >> 4, kk = idx & 15;
            float v = A[(long)(r0 + row) * K + k0 + kk];
            if (RELU_A) v = fmaxf(v, 0.f);
            As[kk][row] = v;
        }
        #pragma unroll
        for (int l = 0; l < 4; ++l) {
            int idx = l * 256 + tid;
            int kk = idx >> 6, col = idx & 63;
            Bs[kk][col] = Bz[(long)(k0 + kk) * M + c0 + col];
        }
        __syncthreads();
        #pragma unroll
        for (int kk = 0; kk < 16; ++kk) {
            float av[4], bv[4];
            #pragma unroll
            for (int i = 0; i < 4; ++i) av[i] = As[kk][ty * 4 + i];
            #pragma unroll
            for (int j = 0; j < 4; ++j) bv[j] = Bs[kk][tx * 4 + j];
            #pragma unroll
            for (int i = 0; i < 4; ++i)
                #pragma unroll
                for (int j = 0; j < 4; ++j) acc[i][j] += av[i] * bv[j];
        }
        __syncthreads();
    }
    #pragma unroll
    for (int i = 0; i < 4; ++i) {
        int r = r0 + ty * 4 + i;
        #pragma unroll
        for (int j = 0; j < 4; ++j) {
            int c = c0 + tx * 4 + j;
            float v = acc[i][j];
            if (BIAS) v += bias[c];
            Cz[(long)r * M + c] = v;
        }
    }
}

// ---------------- af = x1 @ W_adj + b_adj; naf = af / max(||af||, 1e-12) ----------------
__global__ __launch_bounds__(256) void af_naf(
    const float* __restrict__ x1, const float* __restrict__ W_adj,
    const float* __restrict__ b_adj, float* __restrict__ naf)
{
    __shared__ float rowbuf[4][256];
    int tid = threadIdx.x, w = tid >> 6, lane = tid & 63;
    int n = blockIdx.x * 4 + w;
    #pragma unroll
    for (int l = 0; l < 4; ++l) rowbuf[w][l * 64 + lane] = x1[(long)n * 256 + l * 64 + lane];
    __syncthreads();
    float acc = b_adj[lane];
    for (int k = 0; k < 256; ++k) acc += rowbuf[w][k] * W_adj[k * 64 + lane];
    float sq = acc * acc;
    #pragma unroll
    for (int off = 32; off >= 1; off >>= 1) sq += __shfl_xor(sq, off);
    float nrm = fmaxf(sqrtf(sq), 1e-12f);
    naf[(long)n * 64 + lane] = acc / nrm;
}

// ---------------- sim[n][m] = naf[n] . naf[m] (RAW, unscaled) ----------------
__global__ __launch_bounds__(256) void sim_k(
    const float* __restrict__ naf, float* __restrict__ sim)
{
    __shared__ float As[64][68];
    __shared__ float Bs[64][68];
    int tid = threadIdx.x;
    int n0 = blockIdx.x * 64, m0 = blockIdx.y * 64;
    #pragma unroll
    for (int l = 0; l < 16; ++l) {
        int idx = l * 256 + tid;
        int i = idx >> 6, k = idx & 63;
        As[i][k] = naf[(long)(n0 + i) * 64 + k];
        Bs[i][k] = naf[(long)(m0 + i) * 64 + k];
    }
    __syncthreads();
    int ty = tid >> 4, tx = tid & 15;
    float acc[4][4] = {};
    for (int k = 0; k < 64; ++k) {
        float av[4], bv[4];
        #pragma unroll
        for (int i = 0; i < 4; ++i) av[i] = As[ty * 4 + i][k];
        #pragma unroll
        for (int j = 0; j < 4; ++j) bv[j] = Bs[tx * 4 + j][k];
        #pragma unroll
        for (int i = 0; i < 4; ++i)
            #pragma unroll
            for (int j = 0; j < 4; ++j) acc[i][j] += av[i] * bv[j];
    }
    #pragma unroll
    for (int i = 0; i < 4; ++i) {
        int r = n0 + ty * 4 + i;
        #pragma unroll
        for (int j = 0; j < 4; ++j)
            sim[(long)r * NTOT + m0 + tx * 4 + j] = acc[i][j];
    }
}

// ---------------- rinv[n] = guard(1 / sum_m sim[n][m]), fp64-exact sum of rounded sims ----
__global__ __launch_bounds__(256) void rowsum_rinv(
    const float* __restrict__ sim, float* __restrict__ rinv)
{
    int tid = threadIdx.x, w = tid >> 6, lane = tid & 63;
    int n = blockIdx.x * 4 + w;
    const float* row = sim + (long)n * NTOT;
    double s = 0.0;
    for (int i = 0; i < 72; ++i) s += (double)row[i * 64 + lane];
    #pragma unroll
    for (int off = 32; off >= 1; off >>= 1) s += __shfl_xor(s, off);
    if (lane == 0) {
        float rs = (float)s;
        float r = 1.0f / rs;
        if (isinf(r)) r = 0.f;
        rinv[n] = r;
    }
}

// ---------------- f1/f2 dots: f1[h][n] = Wh[h][n] . a[h][:D], f2 = . a[h][D:] ----------------
__global__ __launch_bounds__(256) void dots_k(
    const float* __restrict__ Wh, const float* __restrict__ a,
    float* __restrict__ f1, float* __restrict__ f2, int D)
{
    int tid = threadIdx.x, w = tid >> 6, lane = tid & 63;
    int n = blockIdx.x * 4 + w;
    int h = blockIdx.y;
    const float* row = Wh + ((long)h * NTOT + n) * D;
    const float* a1 = a + (long)h * 2 * D;
    const float* a2 = a1 + D;
    float p1 = 0.f, p2 = 0.f;
    for (int d = lane; d < D; d += 64) {
        float v = row[d];
        p1 += v * a1[d];
        p2 += v * a2[d];
    }
    #pragma unroll
    for (int off = 32; off >= 1; off >>= 1) { p1 += __shfl_xor(p1, off); p2 += __shfl_xor(p2, off); }
    if (lane == 0) { f1[(long)h * NTOT + n] = p1; f2[(long)h * NTOT + n] = p2; }
}

// ---------------- multihead softmax stats ----------------
__global__ __launch_bounds__(256) void mh_stats(
    const float* __restrict__ sim, const float* __restrict__ rinv,
    const float* __restrict__ f1, const float* __restrict__ f2,
    float* __restrict__ mx, float* __restrict__ ci)
{
    int tid = threadIdx.x, w = tid >> 6, lane = tid & 63;
    int n = blockIdx.x * 4 + w;
    float rv = rinv[n];
    float f1v[NH], m[NH], l[NH];
    #pragma unroll
    for (int h = 0; h < NH; ++h) { f1v[h] = f1[(long)h * NTOT + n]; m[h] = -3.0e38f; l[h] = 0.f; }
    const float* arow = sim + (long)n * NTOT;
    for (int i = 0; i < 72; ++i) {
        int mm = i * 64 + lane;
        bool msk = (arow[mm] * rv) > 0.f;
        #pragma unroll
        for (int h = 0; h < NH; ++h) {
            float e = lrelu(f1v[h] + f2[(long)h * NTOT + mm]);
            float s = msk ? e : -9.0e15f;
            if (s <= m[h]) l[h] += __expf(s - m[h]);
            else { l[h] = l[h] * __expf(m[h] - s) + 1.f; m[h] = s; }
        }
    }
    #pragma unroll
    for (int off = 32; off >= 1; off >>= 1) {
        #pragma unroll
        for (int h = 0; h < NH; ++h) {
            float om = __shfl_xor(m[h], off);
            float ol = __shfl_xor(l[h], off);
            float nm = fmaxf(m[h], om);
            l[h] = l[h] * __expf(m[h] - nm) + ol * __expf(om - nm);
            m[h] = nm;
        }
    }
    if (lane == 0) {
        #pragma unroll
        for (int h = 0; h < NH; ++h) { mx[(long)h * NTOT + n] = m[h]; ci[(long)h * NTOT + n] = 1.0f / l[h]; }
    }
}

// ---------------- single-head stats, rows >= TC only ----------------
__global__ __launch_bounds__(256) void s_stats(
    const float* __restrict__ sim, const float* __restrict__ rinv,
    const float* __restrict__ f1, const float* __restrict__ f2,
    float* __restrict__ mx, float* __restrict__ ci)
{
    int tid = threadIdx.x, w = tid >> 6, lane = tid & 63;
    int n = TC + blockIdx.x * 4 + w;
    float rv = rinv[n];
    float f1v = f1[n], m = -3.0e38f, l = 0.f;
    const float* arow = sim + (long)n * NTOT;
    for (int i = 0; i < 72; ++i) {
        int mm = i * 64 + lane;
        float e = lrelu(f1v + f2[mm]);
        float s = ((arow[mm] * rv) > 0.f) ? e : -9.0e15f;
        if (s <= m) l += __expf(s - m);
        else { l = l * __expf(m - s) + 1.f; m = s; }
    }
    #pragma unroll
    for (int off = 32; off >= 1; off >>= 1) {
        float om = __shfl_xor(m, off);
        float ol = __shfl_xor(l, off);
        float nm = fmaxf(m, om);
        l = l * __expf(m - nm) + ol * __expf(om - nm);
        m = nm;
    }
    if (lane == 0) { mx[n] = m; ci[n] = 1.0f / l; }
}

// ---------------- multihead att @ Wh; epilogue x2 = elu(.) + relu(x1) ----------------
__global__ __launch_bounds__(256) void mh_attn(
    const float* __restrict__ sim, const float* __restrict__ rinv,
    const float* __restrict__ f1, const float* __restrict__ f2,
    const float* __restrict__ mx, const float* __restrict__ ci,
    const float* __restrict__ Wh, const float* __restrict__ x1, float* __restrict__ x2)
{
    __shared__ float Ps[64][68];
    __shared__ float Ws[64][68];
    __shared__ float rf1[64], rmx[64], rci[64], rrv[64], rf2[64];
    int tid = threadIdx.x;
    int n0 = blockIdx.x * 64;
    int h = blockIdx.y;
    const float* f1h = f1 + (long)h * NTOT;
    const float* f2h = f2 + (long)h * NTOT;
    const float* mxh = mx + (long)h * NTOT;
    const float* cih = ci + (long)h * NTOT;
    const float* Whh = Wh + (long)h * NTOT * 64;
    if (tid < 64) { rf1[tid] = f1h[n0 + tid]; rmx[tid] = mxh[n0 + tid]; rci[tid] = cih[n0 + tid]; rrv[tid] = rinv[n0 + tid]; }
    int ty = tid >> 4, tx = tid & 15;
    float acc[4][4] = {};
    for (int mt = 0; mt < 72; ++mt) {
        int m0 = mt * 64;
        __syncthreads();
        if (tid < 64) rf2[tid] = f2h[m0 + tid];
        __syncthreads();
        #pragma unroll 4
        for (int l = 0; l < 16; ++l) {
            int idx = l * 256 + tid;
            int i = idx >> 6, j = idx & 63;
            float av = sim[(long)(n0 + i) * NTOT + m0 + j];
            float e = lrelu(rf1[i] + rf2[j]);
            float s = ((av * rrv[i]) > 0.f) ? e : -9.0e15f;
            Ps[i][j] = __expf(s - rmx[i]) * rci[i];
            Ws[i][j] = Whh[(long)(m0 + i) * 64 + j];
        }
        __syncthreads();
        #pragma unroll
        for (int k = 0; k < 64; ++k) {
            float av[4], bv[4];
            #pragma unroll
            for (int i = 0; i < 4; ++i) av[i] = Ps[ty * 4 + i][k];
            #pragma unroll
            for (int j = 0; j < 4; ++j) bv[j] = Ws[k][tx * 4 + j];
            #pragma unroll
            for (int i = 0; i < 4; ++i)
                #pragma unroll
                for (int j = 0; j < 4; ++j) acc[i][j] += av[i] * bv[j];
        }
    }
    #pragma unroll
    for (int i = 0; i < 4; ++i) {
        int r = n0 + ty * 4 + i;
        #pragma unroll
        for (int j = 0; j < 4; ++j) {
            int c = h * 64 + tx * 4 + j;
            float v = elu(acc[i][j]);
            x2[(long)r * 256 + c] = v + fmaxf(x1[(long)r * 256 + c], 0.f);
        }
    }
}

// ---------------- single-head att @ Wh2 (rows >= TC); epilogue x3 = elu(. + x2) ----------------
__global__ __launch_bounds__(256) void s_attn(
    const float* __restrict__ sim, const float* __restrict__ rinv,
    const float* __restrict__ f1, const float* __restrict__ f2,
    const float* __restrict__ mx, const float* __restrict__ ci,
    const float* __restrict__ Wh2, const float* __restrict__ x2, float* __restrict__ x3)
{
    __shared__ float Ps[32][68];
    __shared__ float Ws[64][68];
    __shared__ float rf1[32], rmx[32], rci[32], rrv[32], rf2[64];
    int tid = threadIdx.x;
    int lr0 = blockIdx.x * 32;
    int c0 = blockIdx.y * 64;
    int n0 = TC + lr0;
    if (tid < 32) { rf1[tid] = f1[n0 + tid]; rmx[tid] = mx[n0 + tid]; rci[tid] = ci[n0 + tid]; rrv[tid] = rinv[n0 + tid]; }
    int ty = tid >> 4, tx = tid & 15;
    float acc[2][4] = {};
    for (int mt = 0; mt < 72; ++mt) {
        int m0 = mt * 64;
        __syncthreads();
        if (tid < 64) rf2[tid] = f2[m0 + tid];
        __syncthreads();
        #pragma unroll
        for (int l = 0; l < 8; ++l) {
            int idx = l * 256 + tid;
            int i = idx >> 6, j = idx & 63;
            float av = sim[(long)(n0 + i) * NTOT + m0 + j];
            float e = lrelu(rf1[i] + rf2[j]);
            float s = ((av * rrv[i]) > 0.f) ? e : -9.0e15f;
            Ps[i][j] = __expf(s - rmx[i]) * rci[i];
        }
        #pragma unroll
        for (int l = 0; l < 16; ++l) {
            int idx = l * 256 + tid;
            int mm = idx >> 6, d = idx & 63;
            Ws[mm][d] = Wh2[(long)(m0 + mm) * 256 + c0 + d];
        }
        __syncthreads();
        #pragma unroll
        for (int k = 0; k < 64; ++k) {
            float a2[2], b4[4];
            #pragma unroll
            for (int i = 0; i < 2; ++i) a2[i] = Ps[ty * 2 + i][k];
            #pragma unroll
            for (int j = 0; j < 4; ++j) b4[j] = Ws[k][tx * 4 + j];
            #pragma unroll
            for (int i = 0; i < 2; ++i)
                #pragma unroll
                for (int j = 0; j < 4; ++j) acc[i][j] += a2[i] * b4[j];
        }
    }
    #pragma unroll
    for (int i = 0; i < 2; ++i) {
        int lr = lr0 + ty * 2 + i;
        int n = TC + lr;
        #pragma unroll
        for (int j = 0; j < 4; ++j) {
            int c = c0 + tx * 4 + j;
            float v = acc[i][j] + x2[(long)n * 256 + c];
            x3[(long)lr * 256 + c] = elu(v);
        }
    }
}

// ---------------- bi-softmax phase A: per (ds, rowchunk, col) partial max/sumexp ----------------
__global__ __launch_bounds__(256) void bi_partial(
    const float* __restrict__ sim, const float* __restrict__ rinv,
    float* __restrict__ pmax, float* __restrict__ psum)
{
    int c = blockIdx.x * 256 + threadIdx.x;   // 0..1535
    int ch = blockIdx.y;                       // 0..11
    int ds = blockIdx.z;                       // 0..1
    float m = -3.0e38f, s = 0.f;
    int rbase = ds * MU + ch * 128;
    for (int r = 0; r < 128; ++r) {
        float a = sim[(long)(rbase + r) * NTOT + TC + c] * rinv[rbase + r];
        float v = a * 20.0f;
        if (v <= m) s += expf(v - m);
        else { s = s * expf(m - v) + 1.f; m = v; }
    }
    pmax[((long)ds * 12 + ch) * MU + c] = m;
    psum[((long)ds * 12 + ch) * MU + c] = s;
}

// ---------------- bi-softmax phase B: combine 12 chunks per column ----------------
__global__ __launch_bounds__(256) void bi_combine(
    const float* __restrict__ pmax, const float* __restrict__ psum,
    float* __restrict__ fmax, float* __restrict__ fis)
{
    int b = blockIdx.x;
    int ds = b / 6, ct = b % 6;
    int c = ct * 256 + threadIdx.x;
    float m = -3.0e38f;
    for (int ch = 0; ch < 12; ++ch) m = fmaxf(m, pmax[((long)ds * 12 + ch) * MU + c]);
    float s = 0.f;
    for (int ch = 0; ch < 12; ++ch)
        s += psum[((long)ds * 12 + ch) * MU + c] * expf(pmax[((long)ds * 12 + ch) * MU + c] - m);
    fmax[ds * MU + c] = m;
    fis[ds * MU + c] = 1.0f / s;
}

// ---------------- bi-softmax phase C: normalize & write ----------------
__global__ __launch_bounds__(256) void bi_norm(
    const float* __restrict__ sim, const float* __restrict__ rinv,
    const float* __restrict__ fmax, const float* __restrict__ fis,
    float* __restrict__ outbg)
{
    int c = blockIdx.x * 256 + threadIdx.x;
    int ch = blockIdx.y;
    int ds = blockIdx.z;
    float m = fmax[ds * MU + c], inv = fis[ds * MU + c];
    long obase = (long)ds * MU * MU;
    int rbase = ch * 128;
    for (int r = 0; r < 128; ++r) {
        int row = ds * MU + rbase + r;
        float a = sim[(long)row * NTOT + TC + c] * rinv[row];
        float v = a * 20.0f;
        outbg[obase + (long)(rbase + r) * MU + c] = expf(v - m) * inv;
    }
}

// ---------------- launch ----------------
extern "C" void kernel_launch(void* const* d_in, const int* in_sizes, int n_in,
                              void* d_out, int out_size, void* d_ws, size_t ws_size,
                              hipStream_t stream)
{
    const float* x        = (const float*)d_in[0];
    const float* W_before = (const float*)d_in[1];
    const float* b_before = (const float*)d_in[2];
    const float* W_adj    = (const float*)d_in[3];
    const float* b_adj    = (const float*)d_in[4];
    const float* W_heads  = (const float*)d_in[5];
    const float* a_heads  = (const float*)d_in[6];
    const float* W_out    = (const float*)d_in[7];
    const float* a_out    = (const float*)d_in[8];
    const float* W_lin1   = (const float*)d_in[9];
    const float* b_lin1   = (const float*)d_in[10];
    float* out = (float*)d_out;
    float* ws  = (float*)d_ws;

    float* sim  = ws + OFF_ADJ;
    float* x1p  = ws + OFF_X1;
    float* naf  = ws + OFF_NAF;
    float* rinv = ws + OFF_RINV;
    float* Wh   = ws + OFF_WH;
    float* f1h  = ws + OFF_F1H;
    float* f2h  = ws + OFF_F2H;
    float* mxh  = ws + OFF_MXH;
    float* cih  = ws + OFF_CIH;
    float* x2   = ws + OFF_X2;
    float* Wh2  = ws + OFF_WH2;
    float* f1s  = ws + OFF_F1S;
    float* f2s  = ws + OFF_F2S;
    float* mxs  = ws + OFF_MXS;
    float* cis  = ws + OFF_CIS;
    float* x3   = ws + OFF_X3;
    float* pmax = ws + OFF_PMAX;
    float* psum = ws + OFF_PSUM;
    float* fmx  = ws + OFF_FMAX;
    float* fis  = ws + OFF_FIS;

    dim3 b256(256);

    // x1_pre = x @ W_before + b
    gemm_rm<false, true><<<dim3(72, 4, 1), b256, 0, stream>>>(x, W_before, b_before, x1p, 512, 256, 0, 0);
    // adjacency features
    af_naf<<<dim3(1152), b256, 0, stream>>>(x1p, W_adj, b_adj, naf);
    sim_k<<<dim3(72, 72), b256, 0, stream>>>(naf, sim);
    rowsum_rinv<<<dim3(1152), b256, 0, stream>>>(sim, rinv);
    // multihead: Wh[h] = relu(x1) @ W_heads[h]
    gemm_rm<true, false><<<dim3(72, 1, 4), b256, 0, stream>>>(x1p, W_heads, nullptr, Wh, 256, 64,
                                                              (long)256 * 64, (long)NTOT * 64);
    dots_k<<<dim3(1152, 4), b256, 0, stream>>>(Wh, a_heads, f1h, f2h, 64);
    mh_stats<<<dim3(1152), b256, 0, stream>>>(sim, rinv, f1h, f2h, mxh, cih);
    mh_attn<<<dim3(72, 4), b256, 0, stream>>>(sim, rinv, f1h, f2h, mxh, cih, Wh, x1p, x2);
    // single GAT
    gemm_rm<false, false><<<dim3(72, 4, 1), b256, 0, stream>>>(x2, W_out, nullptr, Wh2, 256, 256, 0, 0);
    dots_k<<<dim3(1152, 1), b256, 0, stream>>>(Wh2, a_out, f1s, f2s, 256);
    s_stats<<<dim3(384), b256, 0, stream>>>(sim, rinv, f1s, f2s, mxs, cis);
    s_attn<<<dim3(48, 4), b256, 0, stream>>>(sim, rinv, f1s, f2s, mxs, cis, Wh2, x2, x3);
    // feat_mlp rows TC.. -> out[0 : 1536*512]
    gemm_rm<false, true><<<dim3(24, 8, 1), b256, 0, stream>>>(x3, W_lin1, b_lin1, out, 256, 512, 0, 0);
    // bi-softmax outputs
    bi_partial<<<dim3(6, 12, 2), b256, 0, stream>>>(sim, rinv, pmax, psum);
    bi_combine<<<dim3(12), b256, 0, stream>>>(pmax, psum, fmx, fis);
    bi_norm<<<dim3(6, 12, 2), b256, 0, stream>>>(sim, rinv, fmx, fis, out + (long)MU * 512);
}

// Round 5
// 722.772 us; speedup vs baseline: 1.3901x; 1.3901x over previous
//
#include <hip/hip_runtime.h>
#include <hip/hip_bf16.h>
#include <math.h>

// Problem constants (from reference)
constexpr int NTOT = 4608;   // N_NODES
constexpr int TC   = 3072;   // TOTAL_CATS
constexpr int MU   = 1536;   // MAX_UNIFY
constexpr int NH   = 4;      // heads

// ---------------- workspace layout (float offsets) ----------------
constexpr long OFF_ADJ  = 0;                                  // N*N raw sim
constexpr long OFF_X1   = OFF_ADJ  + (long)NTOT*NTOT;         // N*256 (pre-relu)
constexpr long OFF_NAF  = OFF_X1   + (long)NTOT*256;          // N*64
constexpr long OFF_PART = OFF_NAF  + (long)NTOT*64;           // (unused)
constexpr long OFF_RINV = OFF_PART + 72*64;                   // N
constexpr long OFF_WH   = OFF_RINV + NTOT;                    // 4*N*64
constexpr long OFF_F1H  = OFF_WH   + (long)4*NTOT*64;         // 4*N
constexpr long OFF_F2H  = OFF_F1H  + (long)4*NTOT;
constexpr long OFF_MXH  = OFF_F2H  + (long)4*NTOT;
constexpr long OFF_CIH  = OFF_MXH  + (long)4*NTOT;
constexpr long OFF_X2   = OFF_CIH  + (long)4*NTOT;            // N*256
constexpr long OFF_WH2  = OFF_X2   + (long)NTOT*256;          // N*256 (also acc1 before Wh2 is produced)
constexpr long OFF_F1S  = OFF_WH2  + (long)NTOT*256;          // N
constexpr long OFF_F2S  = OFF_F1S  + NTOT;
constexpr long OFF_MXS  = OFF_F2S  + NTOT;
constexpr long OFF_CIS  = OFF_MXS  + NTOT;
constexpr long OFF_X3   = OFF_CIS  + NTOT;                    // 1536*256
constexpr long OFF_PMAX = OFF_X3   + (long)MU*256;            // 2*12*1536
constexpr long OFF_PSUM = OFF_PMAX + (long)2*12*MU;
constexpr long OFF_FMAX = OFF_PSUM + (long)2*12*MU;           // 2*1536
constexpr long OFF_FIS  = OFF_FMAX + (long)2*MU;
// acc1 aliases OFF_WH2 (dead until after mh_fin); acc2 aliases OFF_X1 (x1p dead after mh_fin)

__device__ __forceinline__ float lrelu(float x) { return (x >= 0.f) ? x : 0.2f * x; }
__device__ __forceinline__ float elu(float x)   { return (x > 0.f) ? x : expm1f(x); }

// ---------------- zero-fill (float4) ----------------
__global__ __launch_bounds__(256) void zero_k(float* __restrict__ p)
{
    long idx = ((long)blockIdx.x * 256 + threadIdx.x) * 4;
    *(float4*)(p + idx) = make_float4(0.f, 0.f, 0.f, 0.f);
}

// ---------------- generic tiled fp32 GEMM: C = A(NxK) @ B(KxM) [+bias] ----------------
template<bool RELU_A, bool BIAS>
__global__ __launch_bounds__(256) void gemm_rm(
    const float* __restrict__ A, const float* __restrict__ B,
    const float* __restrict__ bias, float* __restrict__ C,
    int K, int M, long strideBz, long strideCz)
{
    __shared__ float As[16][68];
    __shared__ float Bs[16][68];
    const float* Bz = B + (long)blockIdx.z * strideBz;
    float* Cz = C + (long)blockIdx.z * strideCz;
    int tid = threadIdx.x;
    int r0 = blockIdx.x * 64;
    int c0 = blockIdx.y * 64;
    int ty = tid >> 4, tx = tid & 15;
    float acc[4][4] = {};
    for (int k0 = 0; k0 < K; k0 += 16) {
        #pragma unroll
        for (int l = 0; l < 4; ++l) {
            int idx = l * 256 + tid;
            int row = idx >> 4, kk = idx & 15;
            float v = A[(long)(r0 + row) * K + k0 + kk];
            if (RELU_A) v = fmaxf(v, 0.f);
            As[kk][row] = v;
        }
        #pragma unroll
        for (int l = 0; l < 4; ++l) {
            int idx = l * 256 + tid;
            int kk = idx >> 6, col = idx & 63;
            Bs[kk][col] = Bz[(long)(k0 + kk) * M + c0 + col];
        }
        __syncthreads();
        #pragma unroll
        for (int kk = 0; kk < 16; ++kk) {
            float av[4], bv[4];
            #pragma unroll
            for (int i = 0; i < 4; ++i) av[i] = As[kk][ty * 4 + i];
            #pragma unroll
            for (int j = 0; j < 4; ++j) bv[j] = Bs[kk][tx * 4 + j];
            #pragma unroll
            for (int i = 0; i < 4; ++i)
                #pragma unroll
                for (int j = 0; j < 4; ++j) acc[i][j] += av[i] * bv[j];
        }
        __syncthreads();
    }
    #pragma unroll
    for (int i = 0; i < 4; ++i) {
        int r = r0 + ty * 4 + i;
        #pragma unroll
        for (int j = 0; j < 4; ++j) {
            int c = c0 + tx * 4 + j;
            float v = acc[i][j];
            if (BIAS) v += bias[c];
            Cz[(long)r * M + c] = v;
        }
    }
}

// ---------------- af = x1 @ W_adj + b_adj; naf = af / max(||af||, 1e-12) ----------------
__global__ __launch_bounds__(256) void af_naf(
    const float* __restrict__ x1, const float* __restrict__ W_adj,
    const float* __restrict__ b_adj, float* __restrict__ naf)
{
    __shared__ float rowbuf[4][256];
    int tid = threadIdx.x, w = tid >> 6, lane = tid & 63;
    int n = blockIdx.x * 4 + w;
    #pragma unroll
    for (int l = 0; l < 4; ++l) rowbuf[w][l * 64 + lane] = x1[(long)n * 256 + l * 64 + lane];
    __syncthreads();
    float acc = b_adj[lane];
    for (int k = 0; k < 256; ++k) acc += rowbuf[w][k] * W_adj[k * 64 + lane];
    float sq = acc * acc;
    #pragma unroll
    for (int off = 32; off >= 1; off >>= 1) sq += __shfl_xor(sq, off);
    float nrm = fmaxf(sqrtf(sq), 1e-12f);
    naf[(long)n * 64 + lane] = acc / nrm;
}

// ---------------- sim[n][m] = naf[n] . naf[m] (RAW, unscaled) ----------------
__global__ __launch_bounds__(256) void sim_k(
    const float* __restrict__ naf, float* __restrict__ sim)
{
    __shared__ float As[64][68];
    __shared__ float Bs[64][68];
    int tid = threadIdx.x;
    int n0 = blockIdx.x * 64, m0 = blockIdx.y * 64;
    #pragma unroll
    for (int l = 0; l < 16; ++l) {
        int idx = l * 256 + tid;
        int i = idx >> 6, k = idx & 63;
        As[i][k] = naf[(long)(n0 + i) * 64 + k];
        Bs[i][k] = naf[(long)(m0 + i) * 64 + k];
    }
    __syncthreads();
    int ty = tid >> 4, tx = tid & 15;
    float acc[4][4] = {};
    for (int k = 0; k < 64; ++k) {
        float av[4], bv[4];
        #pragma unroll
        for (int i = 0; i < 4; ++i) av[i] = As[ty * 4 + i][k];
        #pragma unroll
        for (int j = 0; j < 4; ++j) bv[j] = Bs[tx * 4 + j][k];
        #pragma unroll
        for (int i = 0; i < 4; ++i)
            #pragma unroll
            for (int j = 0; j < 4; ++j) acc[i][j] += av[i] * bv[j];
    }
    #pragma unroll
    for (int i = 0; i < 4; ++i) {
        int r = n0 + ty * 4 + i;
        #pragma unroll
        for (int j = 0; j < 4; ++j)
            sim[(long)r * NTOT + m0 + tx * 4 + j] = acc[i][j];
    }
}

// ---------------- rinv[n] = guard(1 / sum_m sim[n][m]), fp64-exact sum of rounded sims ----
__global__ __launch_bounds__(256) void rowsum_rinv(
    const float* __restrict__ sim, float* __restrict__ rinv)
{
    int tid = threadIdx.x, w = tid >> 6, lane = tid & 63;
    int n = blockIdx.x * 4 + w;
    const float* row = sim + (long)n * NTOT;
    double s = 0.0;
    for (int i = 0; i < 72; ++i) s += (double)row[i * 64 + lane];
    #pragma unroll
    for (int off = 32; off >= 1; off >>= 1) s += __shfl_xor(s, off);
    if (lane == 0) {
        float rs = (float)s;
        float r = 1.0f / rs;
        if (isinf(r)) r = 0.f;
        rinv[n] = r;
    }
}

// ---------------- f1/f2 dots ----------------
__global__ __launch_bounds__(256) void dots_k(
    const float* __restrict__ Wh, const float* __restrict__ a,
    float* __restrict__ f1, float* __restrict__ f2, int D)
{
    int tid = threadIdx.x, w = tid >> 6, lane = tid & 63;
    int n = blockIdx.x * 4 + w;
    int h = blockIdx.y;
    const float* row = Wh + ((long)h * NTOT + n) * D;
    const float* a1 = a + (long)h * 2 * D;
    const float* a2 = a1 + D;
    float p1 = 0.f, p2 = 0.f;
    for (int d = lane; d < D; d += 64) {
        float v = row[d];
        p1 += v * a1[d];
        p2 += v * a2[d];
    }
    #pragma unroll
    for (int off = 32; off >= 1; off >>= 1) { p1 += __shfl_xor(p1, off); p2 += __shfl_xor(p2, off); }
    if (lane == 0) { f1[(long)h * NTOT + n] = p1; f2[(long)h * NTOT + n] = p2; }
}

// ---------------- multihead softmax stats ----------------
__global__ __launch_bounds__(256) void mh_stats(
    const float* __restrict__ sim, const float* __restrict__ rinv,
    const float* __restrict__ f1, const float* __restrict__ f2,
    float* __restrict__ mx, float* __restrict__ ci)
{
    int tid = threadIdx.x, w = tid >> 6, lane = tid & 63;
    int n = blockIdx.x * 4 + w;
    float rv = rinv[n];
    float f1v[NH], m[NH], l[NH];
    #pragma unroll
    for (int h = 0; h < NH; ++h) { f1v[h] = f1[(long)h * NTOT + n]; m[h] = -3.0e38f; l[h] = 0.f; }
    const float* arow = sim + (long)n * NTOT;
    for (int i = 0; i < 72; ++i) {
        int mm = i * 64 + lane;
        bool msk = (arow[mm] * rv) > 0.f;
        #pragma unroll
        for (int h = 0; h < NH; ++h) {
            float e = lrelu(f1v[h] + f2[(long)h * NTOT + mm]);
            float s = msk ? e : -9.0e15f;
            if (s <= m[h]) l[h] += __expf(s - m[h]);
            else { l[h] = l[h] * __expf(m[h] - s) + 1.f; m[h] = s; }
        }
    }
    #pragma unroll
    for (int off = 32; off >= 1; off >>= 1) {
        #pragma unroll
        for (int h = 0; h < NH; ++h) {
            float om = __shfl_xor(m[h], off);
            float ol = __shfl_xor(l[h], off);
            float nm = fmaxf(m[h], om);
            l[h] = l[h] * __expf(m[h] - nm) + ol * __expf(om - nm);
            m[h] = nm;
        }
    }
    if (lane == 0) {
        #pragma unroll
        for (int h = 0; h < NH; ++h) { mx[(long)h * NTOT + n] = m[h]; ci[(long)h * NTOT + n] = 1.0f / l[h]; }
    }
}

// ---------------- single-head stats, rows >= TC only ----------------
__global__ __launch_bounds__(256) void s_stats(
    const float* __restrict__ sim, const float* __restrict__ rinv,
    const float* __restrict__ f1, const float* __restrict__ f2,
    float* __restrict__ mx, float* __restrict__ ci)
{
    int tid = threadIdx.x, w = tid >> 6, lane = tid & 63;
    int n = TC + blockIdx.x * 4 + w;
    float rv = rinv[n];
    float f1v = f1[n], m = -3.0e38f, l = 0.f;
    const float* arow = sim + (long)n * NTOT;
    for (int i = 0; i < 72; ++i) {
        int mm = i * 64 + lane;
        float e = lrelu(f1v + f2[mm]);
        float s = ((arow[mm] * rv) > 0.f) ? e : -9.0e15f;
        if (s <= m) l += __expf(s - m);
        else { l = l * __expf(m - s) + 1.f; m = s; }
    }
    #pragma unroll
    for (int off = 32; off >= 1; off >>= 1) {
        float om = __shfl_xor(m, off);
        float ol = __shfl_xor(l, off);
        float nm = fmaxf(m, om);
        l = l * __expf(m - nm) + ol * __expf(om - nm);
        m = nm;
    }
    if (lane == 0) { mx[n] = m; ci[n] = 1.0f / l; }
}

// ---------------- multihead att @ Wh, m-split partials into acc via atomics ----------------
// grid (72 n-tiles, 4 heads, 6 m-chunks of 12 tiles)
__global__ __launch_bounds__(256) void mh_attn(
    const float* __restrict__ sim, const float* __restrict__ rinv,
    const float* __restrict__ f1, const float* __restrict__ f2,
    const float* __restrict__ mx, const float* __restrict__ ci,
    const float* __restrict__ Wh, float* __restrict__ accb)
{
    __shared__ float Ps[64][68];
    __shared__ float Ws[64][68];
    __shared__ float rf1[64], rmx[64], rci[64], rrv[64];
    int tid = threadIdx.x;
    int n0 = blockIdx.x * 64;
    int h = blockIdx.y;
    int ch = blockIdx.z;
    const float* f1h = f1 + (long)h * NTOT;
    const float* f2h = f2 + (long)h * NTOT;
    const float* mxh = mx + (long)h * NTOT;
    const float* cih = ci + (long)h * NTOT;
    const float* Whh = Wh + (long)h * NTOT * 64;
    if (tid < 64) { rf1[tid] = f1h[n0 + tid]; rmx[tid] = mxh[n0 + tid]; rci[tid] = cih[n0 + tid]; rrv[tid] = rinv[n0 + tid]; }
    int ty = tid >> 4, tx = tid & 15, jj = (tid & 15) * 4;
    float acc[4][4] = {};
    for (int mt = ch * 12; mt < ch * 12 + 12; ++mt) {
        int m0 = mt * 64;
        float4 f2v = *(const float4*)(f2h + m0 + jj);
        __syncthreads();               // prev GEMM done (also covers rf1 init on first iter)
        #pragma unroll
        for (int l = 0; l < 4; ++l) {
            int i = (l * 256 + tid) >> 4;             // 0..63, each (i,jj) once
            float4 sv = *(const float4*)(sim + (long)(n0 + i) * NTOT + m0 + jj);
            float4 wv = *(const float4*)(Whh + (long)(m0 + i) * 64 + jj);
            float r1 = rf1[i], rm = rmx[i], rc = rci[i], rv = rrv[i];
            float4 pv;
            pv.x = __expf((((sv.x * rv) > 0.f) ? lrelu(r1 + f2v.x) : -9.0e15f) - rm) * rc;
            pv.y = __expf((((sv.y * rv) > 0.f) ? lrelu(r1 + f2v.y) : -9.0e15f) - rm) * rc;
            pv.z = __expf((((sv.z * rv) > 0.f) ? lrelu(r1 + f2v.z) : -9.0e15f) - rm) * rc;
            pv.w = __expf((((sv.w * rv) > 0.f) ? lrelu(r1 + f2v.w) : -9.0e15f) - rm) * rc;
            *(float4*)(&Ps[i][jj]) = pv;
            *(float4*)(&Ws[i][jj]) = wv;
        }
        __syncthreads();
        #pragma unroll
        for (int k = 0; k < 64; ++k) {
            float4 bv = *(const float4*)(&Ws[k][tx * 4]);
            float av[4];
            #pragma unroll
            for (int i = 0; i < 4; ++i) av[i] = Ps[ty * 4 + i][k];
            #pragma unroll
            for (int i = 0; i < 4; ++i) {
                acc[i][0] += av[i] * bv.x;
                acc[i][1] += av[i] * bv.y;
                acc[i][2] += av[i] * bv.z;
                acc[i][3] += av[i] * bv.w;
            }
        }
    }
    #pragma unroll
    for (int i = 0; i < 4; ++i) {
        long r = n0 + ty * 4 + i;
        #pragma unroll
        for (int j = 0; j < 4; ++j)
            atomicAdd(accb + r * 256 + h * 64 + tx * 4 + j, acc[i][j]);
    }
}

// ---------------- mh epilogue: x2 = elu(acc) + relu(x1) ----------------
__global__ __launch_bounds__(256) void mh_fin(
    const float* __restrict__ accb, const float* __restrict__ x1, float* __restrict__ x2)
{
    long idx = ((long)blockIdx.x * 256 + threadIdx.x) * 4;
    float4 a = *(const float4*)(accb + idx);
    float4 xv = *(const float4*)(x1 + idx);
    float4 o;
    o.x = elu(a.x) + fmaxf(xv.x, 0.f);
    o.y = elu(a.y) + fmaxf(xv.y, 0.f);
    o.z = elu(a.z) + fmaxf(xv.z, 0.f);
    o.w = elu(a.w) + fmaxf(xv.w, 0.f);
    *(float4*)(x2 + idx) = o;
}

// ---------------- single-head att @ Wh2 (rows >= TC), m-split partials ----------------
// grid (48 row-tiles of 32, 4 col-tiles of 64, 6 m-chunks of 12 tiles)
__global__ __launch_bounds__(256) void s_attn(
    const float* __restrict__ sim, const float* __restrict__ rinv,
    const float* __restrict__ f1, const float* __restrict__ f2,
    const float* __restrict__ mx, const float* __restrict__ ci,
    const float* __restrict__ Wh2, float* __restrict__ accb)
{
    __shared__ float Ps[32][68];
    __shared__ float Ws[64][68];
    __shared__ float rf1[32], rmx[32], rci[32], rrv[32];
    int tid = threadIdx.x;
    int lr0 = blockIdx.x * 32;
    int c0 = blockIdx.y * 64;
    int ch = blockIdx.z;
    int n0 = TC + lr0;
    if (tid < 32) { rf1[tid] = f1[n0 + tid]; rmx[tid] = mx[n0 + tid]; rci[tid] = ci[n0 + tid]; rrv[tid] = rinv[n0 + tid]; }
    int ty = tid >> 4, tx = tid & 15, jj = (tid & 15) * 4;
    float acc[2][4] = {};
    for (int mt = ch * 12; mt < ch * 12 + 12; ++mt) {
        int m0 = mt * 64;
        float4 f2v = *(const float4*)(f2 + m0 + jj);
        __syncthreads();
        #pragma unroll
        for (int l = 0; l < 4; ++l) {
            int i = (l * 256 + tid) >> 4;             // 0..63 (m rows of Ws)
            *(float4*)(&Ws[i][jj]) = *(const float4*)(Wh2 + (long)(m0 + i) * 256 + c0 + jj);
        }
        #pragma unroll
        for (int l = 0; l < 2; ++l) {
            int i = (l * 256 + tid) >> 4;             // 0..31 (n rows of Ps)
            float4 sv = *(const float4*)(sim + (long)(n0 + i) * NTOT + m0 + jj);
            float r1 = rf1[i], rm = rmx[i], rc = rci[i], rv = rrv[i];
            float4 pv;
            pv.x = __expf((((sv.x * rv) > 0.f) ? lrelu(r1 + f2v.x) : -9.0e15f) - rm) * rc;
            pv.y = __expf((((sv.y * rv) > 0.f) ? lrelu(r1 + f2v.y) : -9.0e15f) - rm) * rc;
            pv.z = __expf((((sv.z * rv) > 0.f) ? lrelu(r1 + f2v.z) : -9.0e15f) - rm) * rc;
            pv.w = __expf((((sv.w * rv) > 0.f) ? lrelu(r1 + f2v.w) : -9.0e15f) - rm) * rc;
            *(float4*)(&Ps[i][jj]) = pv;
        }
        __syncthreads();
        #pragma unroll
        for (int k = 0; k < 64; ++k) {
            float4 bv = *(const float4*)(&Ws[k][tx * 4]);
            float a0 = Ps[ty * 2 + 0][k];
            float a1 = Ps[ty * 2 + 1][k];
            acc[0][0] += a0 * bv.x; acc[0][1] += a0 * bv.y; acc[0][2] += a0 * bv.z; acc[0][3] += a0 * bv.w;
            acc[1][0] += a1 * bv.x; acc[1][1] += a1 * bv.y; acc[1][2] += a1 * bv.z; acc[1][3] += a1 * bv.w;
        }
    }
    #pragma unroll
    for (int i = 0; i < 2; ++i) {
        long r = lr0 + ty * 2 + i;
        #pragma unroll
        for (int j = 0; j < 4; ++j)
            atomicAdd(accb + r * 256 + c0 + tx * 4 + j, acc[i][j]);
    }
}

// ---------------- s epilogue: x3 = elu(acc + x2[TC..]) ----------------
__global__ __launch_bounds__(256) void s_fin(
    const float* __restrict__ accb, const float* __restrict__ x2, float* __restrict__ x3)
{
    long idx = ((long)blockIdx.x * 256 + threadIdx.x) * 4;
    float4 a = *(const float4*)(accb + idx);
    float4 xv = *(const float4*)(x2 + (long)TC * 256 + idx);
    float4 o;
    o.x = elu(a.x + xv.x);
    o.y = elu(a.y + xv.y);
    o.z = elu(a.z + xv.z);
    o.w = elu(a.w + xv.w);
    *(float4*)(x3 + idx) = o;
}

// ---------------- bi-softmax phase A ----------------
__global__ __launch_bounds__(256) void bi_partial(
    const float* __restrict__ sim, const float* __restrict__ rinv,
    float* __restrict__ pmax, float* __restrict__ psum)
{
    int c = blockIdx.x * 256 + threadIdx.x;
    int ch = blockIdx.y;
    int ds = blockIdx.z;
    float m = -3.0e38f, s = 0.f;
    int rbase = ds * MU + ch * 128;
    for (int r = 0; r < 128; ++r) {
        float a = sim[(long)(rbase + r) * NTOT + TC + c] * rinv[rbase + r];
        float v = a * 20.0f;
        if (v <= m) s += expf(v - m);
        else { s = s * expf(m - v) + 1.f; m = v; }
    }
    pmax[((long)ds * 12 + ch) * MU + c] = m;
    psum[((long)ds * 12 + ch) * MU + c] = s;
}

// ---------------- bi-softmax phase B ----------------
__global__ __launch_bounds__(256) void bi_combine(
    const float* __restrict__ pmax, const float* __restrict__ psum,
    float* __restrict__ fmax, float* __restrict__ fis)
{
    int b = blockIdx.x;
    int ds = b / 6, ct = b % 6;
    int c = ct * 256 + threadIdx.x;
    float m = -3.0e38f;
    for (int ch = 0; ch < 12; ++ch) m = fmaxf(m, pmax[((long)ds * 12 + ch) * MU + c]);
    float s = 0.f;
    for (int ch = 0; ch < 12; ++ch)
        s += psum[((long)ds * 12 + ch) * MU + c] * expf(pmax[((long)ds * 12 + ch) * MU + c] - m);
    fmax[ds * MU + c] = m;
    fis[ds * MU + c] = 1.0f / s;
}

// ---------------- bi-softmax phase C ----------------
__global__ __launch_bounds__(256) void bi_norm(
    const float* __restrict__ sim, const float* __restrict__ rinv,
    const float* __restrict__ fmax, const float* __restrict__ fis,
    float* __restrict__ outbg)
{
    int c = blockIdx.x * 256 + threadIdx.x;
    int ch = blockIdx.y;
    int ds = blockIdx.z;
    float m = fmax[ds * MU + c], inv = fis[ds * MU + c];
    long obase = (long)ds * MU * MU;
    int rbase = ch * 128;
    for (int r = 0; r < 128; ++r) {
        int row = ds * MU + rbase + r;
        float a = sim[(long)row * NTOT + TC + c] * rinv[row];
        float v = a * 20.0f;
        outbg[obase + (long)(rbase + r) * MU + c] = expf(v - m) * inv;
    }
}

// ---------------- launch ----------------
extern "C" void kernel_launch(void* const* d_in, const int* in_sizes, int n_in,
                              void* d_out, int out_size, void* d_ws, size_t ws_size,
                              hipStream_t stream)
{
    const float* x        = (const float*)d_in[0];
    const float* W_before = (const float*)d_in[1];
    const float* b_before = (const float*)d_in[2];
    const float* W_adj    = (const float*)d_in[3];
    const float* b_adj    = (const float*)d_in[4];
    const float* W_heads  = (const float*)d_in[5];
    const float* a_heads  = (const float*)d_in[6];
    const float* W_out    = (const float*)d_in[7];
    const float* a_out    = (const float*)d_in[8];
    const float* W_lin1   = (const float*)d_in[9];
    const float* b_lin1   = (const float*)d_in[10];
    float* out = (float*)d_out;
    float* ws  = (float*)d_ws;

    float* sim  = ws + OFF_ADJ;
    float* x1p  = ws + OFF_X1;
    float* naf  = ws + OFF_NAF;
    float* rinv = ws + OFF_RINV;
    float* Wh   = ws + OFF_WH;
    float* f1h  = ws + OFF_F1H;
    float* f2h  = ws + OFF_F2H;
    float* mxh  = ws + OFF_MXH;
    float* cih  = ws + OFF_CIH;
    float* x2   = ws + OFF_X2;
    float* Wh2  = ws + OFF_WH2;
    float* f1s  = ws + OFF_F1S;
    float* f2s  = ws + OFF_F2S;
    float* mxs  = ws + OFF_MXS;
    float* cis  = ws + OFF_CIS;
    float* x3   = ws + OFF_X3;
    float* pmax = ws + OFF_PMAX;
    float* psum = ws + OFF_PSUM;
    float* fmx  = ws + OFF_FMAX;
    float* fis  = ws + OFF_FIS;
    float* acc1 = ws + OFF_WH2;   // alias: dead until Wh2 gemm (after mh_fin)
    float* acc2 = ws + OFF_X1;    // alias: x1p dead after mh_fin

    dim3 b256(256);

    // zero mh partial accumulator (aliases Wh2 region, which isn't produced yet)
    zero_k<<<dim3(NTOT * 256 / 1024), b256, 0, stream>>>(acc1);
    // x1_pre = x @ W_before + b
    gemm_rm<false, true><<<dim3(72, 4, 1), b256, 0, stream>>>(x, W_before, b_before, x1p, 512, 256, 0, 0);
    // adjacency features
    af_naf<<<dim3(1152), b256, 0, stream>>>(x1p, W_adj, b_adj, naf);
    sim_k<<<dim3(72, 72), b256, 0, stream>>>(naf, sim);
    rowsum_rinv<<<dim3(1152), b256, 0, stream>>>(sim, rinv);
    // multihead: Wh[h] = relu(x1) @ W_heads[h]
    gemm_rm<true, false><<<dim3(72, 1, 4), b256, 0, stream>>>(x1p, W_heads, nullptr, Wh, 256, 64,
                                                              (long)256 * 64, (long)NTOT * 64);
    dots_k<<<dim3(1152, 4), b256, 0, stream>>>(Wh, a_heads, f1h, f2h, 64);
    mh_stats<<<dim3(1152), b256, 0, stream>>>(sim, rinv, f1h, f2h, mxh, cih);
    mh_attn<<<dim3(72, 4, 6), b256, 0, stream>>>(sim, rinv, f1h, f2h, mxh, cih, Wh, acc1);
    mh_fin<<<dim3(NTOT * 256 / 1024), b256, 0, stream>>>(acc1, x1p, x2);
    // zero s partial accumulator (aliases x1p, now dead)
    zero_k<<<dim3(MU * 256 / 1024), b256, 0, stream>>>(acc2);
    // single GAT
    gemm_rm<false, false><<<dim3(72, 4, 1), b256, 0, stream>>>(x2, W_out, nullptr, Wh2, 256, 256, 0, 0);
    dots_k<<<dim3(1152, 1), b256, 0, stream>>>(Wh2, a_out, f1s, f2s, 256);
    s_stats<<<dim3(384), b256, 0, stream>>>(sim, rinv, f1s, f2s, mxs, cis);
    s_attn<<<dim3(48, 4, 6), b256, 0, stream>>>(sim, rinv, f1s, f2s, mxs, cis, Wh2, acc2);
    s_fin<<<dim3(MU * 256 / 1024), b256, 0, stream>>>(acc2, x2, x3);
    // feat_mlp rows TC.. -> out[0 : 1536*512]
    gemm_rm<false, true><<<dim3(24, 8, 1), b256, 0, stream>>>(x3, W_lin1, b_lin1, out, 256, 512, 0, 0);
    // bi-softmax outputs
    bi_partial<<<dim3(6, 12, 2), b256, 0, stream>>>(sim, rinv, pmax, psum);
    bi_combine<<<dim3(12), b256, 0, stream>>>(pmax, psum, fmx, fis);
    bi_norm<<<dim3(6, 12, 2), b256, 0, stream>>>(sim, rinv, fmx, fis, out + (long)MU * 512);
}

// Round 6
// 585.442 us; speedup vs baseline: 1.7162x; 1.2346x over previous
//
#include <hip/hip_runtime.h>
#include <hip/hip_bf16.h>
#include <math.h>

// Problem constants (from reference)
constexpr int NTOT = 4608;   // N_NODES
constexpr int TC   = 3072;   // TOTAL_CATS
constexpr int MU   = 1536;   // MAX_UNIFY
constexpr int NH   = 4;      // heads

// ---------------- workspace layout (float offsets) ----------------
constexpr long OFF_ADJ  = 0;                                  // N*N raw sim
constexpr long OFF_X1   = OFF_ADJ  + (long)NTOT*NTOT;         // N*256 (pre-relu)
constexpr long OFF_NAF  = OFF_X1   + (long)NTOT*256;          // N*64
constexpr long OFF_PART = OFF_NAF  + (long)NTOT*64;           // (unused)
constexpr long OFF_RINV = OFF_PART + 72*64;                   // N
constexpr long OFF_WH   = OFF_RINV + NTOT;                    // 4*N*64
constexpr long OFF_F1H  = OFF_WH   + (long)4*NTOT*64;         // 4*N
constexpr long OFF_F2H  = OFF_F1H  + (long)4*NTOT;
constexpr long OFF_MXH  = OFF_F2H  + (long)4*NTOT;
constexpr long OFF_CIH  = OFF_MXH  + (long)4*NTOT;
constexpr long OFF_X2   = OFF_CIH  + (long)4*NTOT;            // N*256
constexpr long OFF_WH2  = OFF_X2   + (long)NTOT*256;          // N*256 (acc1 before Wh2 exists)
constexpr long OFF_F1S  = OFF_WH2  + (long)NTOT*256;          // N
constexpr long OFF_F2S  = OFF_F1S  + NTOT;
constexpr long OFF_MXS  = OFF_F2S  + NTOT;
constexpr long OFF_CIS  = OFF_MXS  + NTOT;
constexpr long OFF_X3   = OFF_CIS  + NTOT;                    // 1536*256
constexpr long OFF_PMAX = OFF_X3   + (long)MU*256;            // 2*12*1536
constexpr long OFF_PSUM = OFF_PMAX + (long)2*12*MU;
constexpr long OFF_FMAX = OFF_PSUM + (long)2*12*MU;           // 2*1536
constexpr long OFF_FIS  = OFF_FMAX + (long)2*MU;
// acc1 aliases OFF_WH2 (dead until after mh_fin); acc2 aliases OFF_X1 (x1p dead after mh_fin)

typedef __attribute__((ext_vector_type(8))) short bf16x8;
typedef __attribute__((ext_vector_type(4))) float floatx4;

__device__ __forceinline__ float lrelu(float x) { return (x >= 0.f) ? x : 0.2f * x; }
__device__ __forceinline__ float elu(float x)   { return (x > 0.f) ? x : expm1f(x); }
__device__ __forceinline__ unsigned short f2bf(float f) {
    unsigned u = __float_as_uint(f);
    u += 0x7FFFu + ((u >> 16) & 1u);           // round-to-nearest-even
    return (unsigned short)(u >> 16);
}

// ---------------- zero-fill (float4) ----------------
__global__ __launch_bounds__(256) void zero_k(float* __restrict__ p)
{
    long idx = ((long)blockIdx.x * 256 + threadIdx.x) * 4;
    *(float4*)(p + idx) = make_float4(0.f, 0.f, 0.f, 0.f);
}

// ---------------- generic tiled fp32 GEMM: C = A(NxK) @ B(KxM) [+bias] ----------------
template<bool RELU_A, bool BIAS>
__global__ __launch_bounds__(256) void gemm_rm(
    const float* __restrict__ A, const float* __restrict__ B,
    const float* __restrict__ bias, float* __restrict__ C,
    int K, int M, long strideBz, long strideCz)
{
    __shared__ float As[16][68];
    __shared__ float Bs[16][68];
    const float* Bz = B + (long)blockIdx.z * strideBz;
    float* Cz = C + (long)blockIdx.z * strideCz;
    int tid = threadIdx.x;
    int r0 = blockIdx.x * 64;
    int c0 = blockIdx.y * 64;
    int ty = tid >> 4, tx = tid & 15;
    float acc[4][4] = {};
    for (int k0 = 0; k0 < K; k0 += 16) {
        #pragma unroll
        for (int l = 0; l < 4; ++l) {
            int idx = l * 256 + tid;
            int row = idx >> 4, kk = idx & 15;
            float v = A[(long)(r0 + row) * K + k0 + kk];
            if (RELU_A) v = fmaxf(v, 0.f);
            As[kk][row] = v;
        }
        #pragma unroll
        for (int l = 0; l < 4; ++l) {
            int idx = l * 256 + tid;
            int kk = idx >> 6, col = idx & 63;
            Bs[kk][col] = Bz[(long)(k0 + kk) * M + c0 + col];
        }
        __syncthreads();
        #pragma unroll
        for (int kk = 0; kk < 16; ++kk) {
            float av[4], bv[4];
            #pragma unroll
            for (int i = 0; i < 4; ++i) av[i] = As[kk][ty * 4 + i];
            #pragma unroll
            for (int j = 0; j < 4; ++j) bv[j] = Bs[kk][tx * 4 + j];
            #pragma unroll
            for (int i = 0; i < 4; ++i)
                #pragma unroll
                for (int j = 0; j < 4; ++j) acc[i][j] += av[i] * bv[j];
        }
        __syncthreads();
    }
    #pragma unroll
    for (int i = 0; i < 4; ++i) {
        int r = r0 + ty * 4 + i;
        #pragma unroll
        for (int j = 0; j < 4; ++j) {
            int c = c0 + tx * 4 + j;
            float v = acc[i][j];
            if (BIAS) v += bias[c];
            Cz[(long)r * M + c] = v;
        }
    }
}

// ---------------- af = x1 @ W_adj + b_adj; naf = af / max(||af||, 1e-12) ----------------
__global__ __launch_bounds__(256) void af_naf(
    const float* __restrict__ x1, const float* __restrict__ W_adj,
    const float* __restrict__ b_adj, float* __restrict__ naf)
{
    __shared__ float rowbuf[4][256];
    int tid = threadIdx.x, w = tid >> 6, lane = tid & 63;
    int n = blockIdx.x * 4 + w;
    #pragma unroll
    for (int l = 0; l < 4; ++l) rowbuf[w][l * 64 + lane] = x1[(long)n * 256 + l * 64 + lane];
    __syncthreads();
    float acc = b_adj[lane];
    for (int k = 0; k < 256; ++k) acc += rowbuf[w][k] * W_adj[k * 64 + lane];
    float sq = acc * acc;
    #pragma unroll
    for (int off = 32; off >= 1; off >>= 1) sq += __shfl_xor(sq, off);
    float nrm = fmaxf(sqrtf(sq), 1e-12f);
    naf[(long)n * 64 + lane] = acc / nrm;
}

// ---------------- sim[n][m] = naf[n] . naf[m] (RAW, unscaled) ----------------
__global__ __launch_bounds__(256) void sim_k(
    const float* __restrict__ naf, float* __restrict__ sim)
{
    __shared__ float As[64][68];
    __shared__ float Bs[64][68];
    int tid = threadIdx.x;
    int n0 = blockIdx.x * 64, m0 = blockIdx.y * 64;
    #pragma unroll
    for (int l = 0; l < 16; ++l) {
        int idx = l * 256 + tid;
        int i = idx >> 6, k = idx & 63;
        As[i][k] = naf[(long)(n0 + i) * 64 + k];
        Bs[i][k] = naf[(long)(m0 + i) * 64 + k];
    }
    __syncthreads();
    int ty = tid >> 4, tx = tid & 15;
    float acc[4][4] = {};
    for (int k = 0; k < 64; ++k) {
        float av[4], bv[4];
        #pragma unroll
        for (int i = 0; i < 4; ++i) av[i] = As[ty * 4 + i][k];
        #pragma unroll
        for (int j = 0; j < 4; ++j) bv[j] = Bs[tx * 4 + j][k];
        #pragma unroll
        for (int i = 0; i < 4; ++i)
            #pragma unroll
            for (int j = 0; j < 4; ++j) acc[i][j] += av[i] * bv[j];
    }
    #pragma unroll
    for (int i = 0; i < 4; ++i) {
        int r = n0 + ty * 4 + i;
        #pragma unroll
        for (int j = 0; j < 4; ++j)
            sim[(long)r * NTOT + m0 + tx * 4 + j] = acc[i][j];
    }
}

// ---------------- rinv[n] = guard(1 / sum_m sim[n][m]), fp64-exact sum of rounded sims ----
__global__ __launch_bounds__(256) void rowsum_rinv(
    const float* __restrict__ sim, float* __restrict__ rinv)
{
    int tid = threadIdx.x, w = tid >> 6, lane = tid & 63;
    int n = blockIdx.x * 4 + w;
    const float* row = sim + (long)n * NTOT;
    double s = 0.0;
    for (int i = 0; i < 72; ++i) s += (double)row[i * 64 + lane];
    #pragma unroll
    for (int off = 32; off >= 1; off >>= 1) s += __shfl_xor(s, off);
    if (lane == 0) {
        float rs = (float)s;
        float r = 1.0f / rs;
        if (isinf(r)) r = 0.f;
        rinv[n] = r;
    }
}

// ---------------- f1/f2 dots ----------------
__global__ __launch_bounds__(256) void dots_k(
    const float* __restrict__ Wh, const float* __restrict__ a,
    float* __restrict__ f1, float* __restrict__ f2, int D)
{
    int tid = threadIdx.x, w = tid >> 6, lane = tid & 63;
    int n = blockIdx.x * 4 + w;
    int h = blockIdx.y;
    const float* row = Wh + ((long)h * NTOT + n) * D;
    const float* a1 = a + (long)h * 2 * D;
    const float* a2 = a1 + D;
    float p1 = 0.f, p2 = 0.f;
    for (int d = lane; d < D; d += 64) {
        float v = row[d];
        p1 += v * a1[d];
        p2 += v * a2[d];
    }
    #pragma unroll
    for (int off = 32; off >= 1; off >>= 1) { p1 += __shfl_xor(p1, off); p2 += __shfl_xor(p2, off); }
    if (lane == 0) { f1[(long)h * NTOT + n] = p1; f2[(long)h * NTOT + n] = p2; }
}

// ---------------- multihead softmax stats ----------------
__global__ __launch_bounds__(256) void mh_stats(
    const float* __restrict__ sim, const float* __restrict__ rinv,
    const float* __restrict__ f1, const float* __restrict__ f2,
    float* __restrict__ mx, float* __restrict__ ci)
{
    int tid = threadIdx.x, w = tid >> 6, lane = tid & 63;
    int n = blockIdx.x * 4 + w;
    float rv = rinv[n];
    float f1v[NH], m[NH], l[NH];
    #pragma unroll
    for (int h = 0; h < NH; ++h) { f1v[h] = f1[(long)h * NTOT + n]; m[h] = -3.0e38f; l[h] = 0.f; }
    const float* arow = sim + (long)n * NTOT;
    for (int i = 0; i < 72; ++i) {
        int mm = i * 64 + lane;
        bool msk = (arow[mm] * rv) > 0.f;
        #pragma unroll
        for (int h = 0; h < NH; ++h) {
            float e = lrelu(f1v[h] + f2[(long)h * NTOT + mm]);
            float s = msk ? e : -9.0e15f;
            if (s <= m[h]) l[h] += __expf(s - m[h]);
            else { l[h] = l[h] * __expf(m[h] - s) + 1.f; m[h] = s; }
        }
    }
    #pragma unroll
    for (int off = 32; off >= 1; off >>= 1) {
        #pragma unroll
        for (int h = 0; h < NH; ++h) {
            float om = __shfl_xor(m[h], off);
            float ol = __shfl_xor(l[h], off);
            float nm = fmaxf(m[h], om);
            l[h] = l[h] * __expf(m[h] - nm) + ol * __expf(om - nm);
            m[h] = nm;
        }
    }
    if (lane == 0) {
        #pragma unroll
        for (int h = 0; h < NH; ++h) { mx[(long)h * NTOT + n] = m[h]; ci[(long)h * NTOT + n] = 1.0f / l[h]; }
    }
}

// ---------------- single-head stats, rows >= TC only ----------------
__global__ __launch_bounds__(256) void s_stats(
    const float* __restrict__ sim, const float* __restrict__ rinv,
    const float* __restrict__ f1, const float* __restrict__ f2,
    float* __restrict__ mx, float* __restrict__ ci)
{
    int tid = threadIdx.x, w = tid >> 6, lane = tid & 63;
    int n = TC + blockIdx.x * 4 + w;
    float rv = rinv[n];
    float f1v = f1[n], m = -3.0e38f, l = 0.f;
    const float* arow = sim + (long)n * NTOT;
    for (int i = 0; i < 72; ++i) {
        int mm = i * 64 + lane;
        float e = lrelu(f1v + f2[mm]);
        float s = ((arow[mm] * rv) > 0.f) ? e : -9.0e15f;
        if (s <= m) l += __expf(s - m);
        else { l = l * __expf(m - s) + 1.f; m = s; }
    }
    #pragma unroll
    for (int off = 32; off >= 1; off >>= 1) {
        float om = __shfl_xor(m, off);
        float ol = __shfl_xor(l, off);
        float nm = fmaxf(m, om);
        l = l * __expf(m - nm) + ol * __expf(om - nm);
        m = nm;
    }
    if (lane == 0) { mx[n] = m; ci[n] = 1.0f / l; }
}

// ---------------- multihead att @ Wh via bf16 MFMA, m-split partials via atomics ----------------
// grid (72 n-tiles, 4 heads, 6 m-chunks of 12 tiles). LDS ~19.5 KB.
__global__ __launch_bounds__(256) void mh_attn(
    const float* __restrict__ sim, const float* __restrict__ rinv,
    const float* __restrict__ f1, const float* __restrict__ f2,
    const float* __restrict__ mx, const float* __restrict__ ci,
    const float* __restrict__ Wh, float* __restrict__ accb)
{
    __shared__ unsigned short Ps[64][72];   // P tile, row-major [n][m] bf16 (A operand); pitch 144B = 16B-mult
    __shared__ unsigned short Ws[64][72];   // Wh tile TRANSPOSED [d][k] bf16 (B operand)
    __shared__ float rf1[64], rmx[64], rci[64], rrv[64];
    int tid = threadIdx.x;
    int wave = tid >> 6, lane = tid & 63;
    int n0 = blockIdx.x * 64;
    int h = blockIdx.y, ch = blockIdx.z;
    const float* f1h = f1 + (long)h * NTOT;
    const float* f2h = f2 + (long)h * NTOT;
    const float* mxh = mx + (long)h * NTOT;
    const float* cih = ci + (long)h * NTOT;
    const float* Whh = Wh + (long)h * NTOT * 64;
    if (tid < 64) { rf1[tid] = f1h[n0 + tid]; rmx[tid] = mxh[n0 + tid]; rci[tid] = cih[n0 + tid]; rrv[tid] = rinv[n0 + tid]; }
    __syncthreads();
    // staging roles: P: row pi, 16 cols from pj. Ws: col d=wd, 16 k's from wk.
    int pi = tid >> 2, pj = (tid & 3) * 16;
    int wd = tid & 63, wk = (tid >> 6) * 16;
    float r1 = rf1[pi], rm = rmx[pi], rc = rci[pi], rv = rrv[pi];
    floatx4 acc[4] = {};
    for (int mt = ch * 12; mt < ch * 12 + 12; ++mt) {
        int m0 = mt * 64;
        __syncthreads();      // prior MFMA reads done
        #pragma unroll
        for (int q = 0; q < 4; ++q) {
            int mc = pj + q * 4;
            float4 sv = *(const float4*)(sim + (long)(n0 + pi) * NTOT + m0 + mc);
            float4 fv = *(const float4*)(f2h + m0 + mc);
            ushort4 pv;
            pv.x = f2bf(__expf((((sv.x * rv) > 0.f) ? lrelu(r1 + fv.x) : -9.0e15f) - rm) * rc);
            pv.y = f2bf(__expf((((sv.y * rv) > 0.f) ? lrelu(r1 + fv.y) : -9.0e15f) - rm) * rc);
            pv.z = f2bf(__expf((((sv.z * rv) > 0.f) ? lrelu(r1 + fv.z) : -9.0e15f) - rm) * rc);
            pv.w = f2bf(__expf((((sv.w * rv) > 0.f) ? lrelu(r1 + fv.w) : -9.0e15f) - rm) * rc);
            *(ushort4*)&Ps[pi][mc] = pv;
        }
        #pragma unroll
        for (int q = 0; q < 4; ++q) {
            int k = wk + q * 4;
            ushort4 wv;   // coalesced across lanes (wd consecutive)
            wv.x = f2bf(Whh[(long)(m0 + k + 0) * 64 + wd]);
            wv.y = f2bf(Whh[(long)(m0 + k + 1) * 64 + wd]);
            wv.z = f2bf(Whh[(long)(m0 + k + 2) * 64 + wd]);
            wv.w = f2bf(Whh[(long)(m0 + k + 3) * 64 + wd]);
            *(ushort4*)&Ws[wd][k] = wv;
        }
        __syncthreads();
        #pragma unroll
        for (int ks = 0; ks < 2; ++ks) {
            bf16x8 af = *(bf16x8*)&Ps[16 * wave + (lane & 15)][ks * 32 + (lane >> 4) * 8];
            #pragma unroll
            for (int dt = 0; dt < 4; ++dt) {
                bf16x8 bfr = *(bf16x8*)&Ws[16 * dt + (lane & 15)][ks * 32 + (lane >> 4) * 8];
                acc[dt] = __builtin_amdgcn_mfma_f32_16x16x32_bf16(af, bfr, acc[dt], 0, 0, 0);
            }
        }
    }
    // C/D layout: col = lane&15, row = (lane>>4)*4 + reg   [m89-verified]
    int crow = n0 + 16 * wave + (lane >> 4) * 4;
    int ccol = h * 64 + (lane & 15);
    #pragma unroll
    for (int dt = 0; dt < 4; ++dt)
        #pragma unroll
        for (int r = 0; r < 4; ++r)
            atomicAdd(accb + (long)(crow + r) * 256 + ccol + dt * 16, acc[dt][r]);
}

// ---------------- mh epilogue: x2 = elu(acc) + relu(x1) ----------------
__global__ __launch_bounds__(256) void mh_fin(
    const float* __restrict__ accb, const float* __restrict__ x1, float* __restrict__ x2)
{
    long idx = ((long)blockIdx.x * 256 + threadIdx.x) * 4;
    float4 a = *(const float4*)(accb + idx);
    float4 xv = *(const float4*)(x1 + idx);
    float4 o;
    o.x = elu(a.x) + fmaxf(xv.x, 0.f);
    o.y = elu(a.y) + fmaxf(xv.y, 0.f);
    o.z = elu(a.z) + fmaxf(xv.z, 0.f);
    o.w = elu(a.w) + fmaxf(xv.w, 0.f);
    *(float4*)(x2 + idx) = o;
}

// ---------------- single-head att @ Wh2 via bf16 MFMA (rows >= TC), m-split partials ----------------
// grid (48 row-tiles of 32, 4 col-tiles of 64, 6 m-chunks). LDS ~14.4 KB.
__global__ __launch_bounds__(256) void s_attn(
    const float* __restrict__ sim, const float* __restrict__ rinv,
    const float* __restrict__ f1, const float* __restrict__ f2,
    const float* __restrict__ mx, const float* __restrict__ ci,
    const float* __restrict__ Wh2, float* __restrict__ accb)
{
    __shared__ unsigned short Ps[32][72];   // P tile [n][m] bf16
    __shared__ unsigned short Ws[64][72];   // Wh2 tile transposed [d][k] bf16
    __shared__ float rf1[32], rmx[32], rci[32], rrv[32];
    int tid = threadIdx.x;
    int wave = tid >> 6, lane = tid & 63;
    int lr0 = blockIdx.x * 32;
    int c0 = blockIdx.y * 64;
    int ch = blockIdx.z;
    int n0 = TC + lr0;
    if (tid < 32) { rf1[tid] = f1[n0 + tid]; rmx[tid] = mx[n0 + tid]; rci[tid] = ci[n0 + tid]; rrv[tid] = rinv[n0 + tid]; }
    __syncthreads();
    int pi = tid >> 3, pj = (tid & 7) * 8;      // P: row 0..31, 8 cols
    int wd = tid & 63, wk = (tid >> 6) * 16;    // Ws: d, 16 k's
    float r1 = rf1[pi], rm = rmx[pi], rc = rci[pi], rv = rrv[pi];
    int rt = wave & 1;                           // row-tile (16 rows)
    int dt0 = (wave >> 1) * 2;                   // first of 2 d-tiles
    floatx4 acc[2] = {};
    for (int mt = ch * 12; mt < ch * 12 + 12; ++mt) {
        int m0 = mt * 64;
        __syncthreads();
        #pragma unroll
        for (int q = 0; q < 2; ++q) {
            int mc = pj + q * 4;
            float4 sv = *(const float4*)(sim + (long)(n0 + pi) * NTOT + m0 + mc);
            float4 fv = *(const float4*)(f2 + m0 + mc);
            ushort4 pv;
            pv.x = f2bf(__expf((((sv.x * rv) > 0.f) ? lrelu(r1 + fv.x) : -9.0e15f) - rm) * rc);
            pv.y = f2bf(__expf((((sv.y * rv) > 0.f) ? lrelu(r1 + fv.y) : -9.0e15f) - rm) * rc);
            pv.z = f2bf(__expf((((sv.z * rv) > 0.f) ? lrelu(r1 + fv.z) : -9.0e15f) - rm) * rc);
            pv.w = f2bf(__expf((((sv.w * rv) > 0.f) ? lrelu(r1 + fv.w) : -9.0e15f) - rm) * rc);
            *(ushort4*)&Ps[pi][mc] = pv;
        }
        #pragma unroll
        for (int q = 0; q < 4; ++q) {
            int k = wk + q * 4;
            ushort4 wv;
            wv.x = f2bf(Wh2[(long)(m0 + k + 0) * 256 + c0 + wd]);
            wv.y = f2bf(Wh2[(long)(m0 + k + 1) * 256 + c0 + wd]);
            wv.z = f2bf(Wh2[(long)(m0 + k + 2) * 256 + c0 + wd]);
            wv.w = f2bf(Wh2[(long)(m0 + k + 3) * 256 + c0 + wd]);
            *(ushort4*)&Ws[wd][k] = wv;
        }
        __syncthreads();
        #pragma unroll
        for (int ks = 0; ks < 2; ++ks) {
            bf16x8 af = *(bf16x8*)&Ps[16 * rt + (lane & 15)][ks * 32 + (lane >> 4) * 8];
            #pragma unroll
            for (int t = 0; t < 2; ++t) {
                bf16x8 bfr = *(bf16x8*)&Ws[16 * (dt0 + t) + (lane & 15)][ks * 32 + (lane >> 4) * 8];
                acc[t] = __builtin_amdgcn_mfma_f32_16x16x32_bf16(af, bfr, acc[t], 0, 0, 0);
            }
        }
    }
    int crow = lr0 + 16 * rt + (lane >> 4) * 4;
    int ccol = c0 + (lane & 15);
    #pragma unroll
    for (int t = 0; t < 2; ++t)
        #pragma unroll
        for (int r = 0; r < 4; ++r)
            atomicAdd(accb + (long)(crow + r) * 256 + ccol + (dt0 + t) * 16, acc[t][r]);
}

// ---------------- s epilogue: x3 = elu(acc + x2[TC..]) ----------------
__global__ __launch_bounds__(256) void s_fin(
    const float* __restrict__ accb, const float* __restrict__ x2, float* __restrict__ x3)
{
    long idx = ((long)blockIdx.x * 256 + threadIdx.x) * 4;
    float4 a = *(const float4*)(accb + idx);
    float4 xv = *(const float4*)(x2 + (long)TC * 256 + idx);
    float4 o;
    o.x = elu(a.x + xv.x);
    o.y = elu(a.y + xv.y);
    o.z = elu(a.z + xv.z);
    o.w = elu(a.w + xv.w);
    *(float4*)(x3 + idx) = o;
}

// ---------------- bi-softmax phase A ----------------
__global__ __launch_bounds__(256) void bi_partial(
    const float* __restrict__ sim, const float* __restrict__ rinv,
    float* __restrict__ pmax, float* __restrict__ psum)
{
    int c = blockIdx.x * 256 + threadIdx.x;
    int ch = blockIdx.y;
    int ds = blockIdx.z;
    float m = -3.0e38f, s = 0.f;
    int rbase = ds * MU + ch * 128;
    for (int r = 0; r < 128; ++r) {
        float a = sim[(long)(rbase + r) * NTOT + TC + c] * rinv[rbase + r];
        float v = a * 20.0f;
        if (v <= m) s += expf(v - m);
        else { s = s * expf(m - v) + 1.f; m = v; }
    }
    pmax[((long)ds * 12 + ch) * MU + c] = m;
    psum[((long)ds * 12 + ch) * MU + c] = s;
}

// ---------------- bi-softmax phase B ----------------
__global__ __launch_bounds__(256) void bi_combine(
    const float* __restrict__ pmax, const float* __restrict__ psum,
    float* __restrict__ fmax, float* __restrict__ fis)
{
    int b = blockIdx.x;
    int ds = b / 6, ct = b % 6;
    int c = ct * 256 + threadIdx.x;
    float m = -3.0e38f;
    for (int ch = 0; ch < 12; ++ch) m = fmaxf(m, pmax[((long)ds * 12 + ch) * MU + c]);
    float s = 0.f;
    for (int ch = 0; ch < 12; ++ch)
        s += psum[((long)ds * 12 + ch) * MU + c] * expf(pmax[((long)ds * 12 + ch) * MU + c] - m);
    fmax[ds * MU + c] = m;
    fis[ds * MU + c] = 1.0f / s;
}

// ---------------- bi-softmax phase C ----------------
__global__ __launch_bounds__(256) void bi_norm(
    const float* __restrict__ sim, const float* __restrict__ rinv,
    const float* __restrict__ fmax, const float* __restrict__ fis,
    float* __restrict__ outbg)
{
    int c = blockIdx.x * 256 + threadIdx.x;
    int ch = blockIdx.y;
    int ds = blockIdx.z;
    float m = fmax[ds * MU + c], inv = fis[ds * MU + c];
    long obase = (long)ds * MU * MU;
    int rbase = ch * 128;
    for (int r = 0; r < 128; ++r) {
        int row = ds * MU + rbase + r;
        float a = sim[(long)row * NTOT + TC + c] * rinv[row];
        float v = a * 20.0f;
        outbg[obase + (long)(rbase + r) * MU + c] = expf(v - m) * inv;
    }
}

// ---------------- launch ----------------
extern "C" void kernel_launch(void* const* d_in, const int* in_sizes, int n_in,
                              void* d_out, int out_size, void* d_ws, size_t ws_size,
                              hipStream_t stream)
{
    const float* x        = (const float*)d_in[0];
    const float* W_before = (const float*)d_in[1];
    const float* b_before = (const float*)d_in[2];
    const float* W_adj    = (const float*)d_in[3];
    const float* b_adj    = (const float*)d_in[4];
    const float* W_heads  = (const float*)d_in[5];
    const float* a_heads  = (const float*)d_in[6];
    const float* W_out    = (const float*)d_in[7];
    const float* a_out    = (const float*)d_in[8];
    const float* W_lin1   = (const float*)d_in[9];
    const float* b_lin1   = (const float*)d_in[10];
    float* out = (float*)d_out;
    float* ws  = (float*)d_ws;

    float* sim  = ws + OFF_ADJ;
    float* x1p  = ws + OFF_X1;
    float* naf  = ws + OFF_NAF;
    float* rinv = ws + OFF_RINV;
    float* Wh   = ws + OFF_WH;
    float* f1h  = ws + OFF_F1H;
    float* f2h  = ws + OFF_F2H;
    float* mxh  = ws + OFF_MXH;
    float* cih  = ws + OFF_CIH;
    float* x2   = ws + OFF_X2;
    float* Wh2  = ws + OFF_WH2;
    float* f1s  = ws + OFF_F1S;
    float* f2s  = ws + OFF_F2S;
    float* mxs  = ws + OFF_MXS;
    float* cis  = ws + OFF_CIS;
    float* x3   = ws + OFF_X3;
    float* pmax = ws + OFF_PMAX;
    float* psum = ws + OFF_PSUM;
    float* fmx  = ws + OFF_FMAX;
    float* fis  = ws + OFF_FIS;
    float* acc1 = ws + OFF_WH2;   // alias: dead until Wh2 gemm (after mh_fin)
    float* acc2 = ws + OFF_X1;    // alias: x1p dead after mh_fin

    dim3 b256(256);

    // zero mh partial accumulator (aliases Wh2 region, which isn't produced yet)
    zero_k<<<dim3(NTOT * 256 / 1024), b256, 0, stream>>>(acc1);
    // x1_pre = x @ W_before + b
    gemm_rm<false, true><<<dim3(72, 4, 1), b256, 0, stream>>>(x, W_before, b_before, x1p, 512, 256, 0, 0);
    // adjacency features
    af_naf<<<dim3(1152), b256, 0, stream>>>(x1p, W_adj, b_adj, naf);
    sim_k<<<dim3(72, 72), b256, 0, stream>>>(naf, sim);
    rowsum_rinv<<<dim3(1152), b256, 0, stream>>>(sim, rinv);
    // multihead: Wh[h] = relu(x1) @ W_heads[h]
    gemm_rm<true, false><<<dim3(72, 1, 4), b256, 0, stream>>>(x1p, W_heads, nullptr, Wh, 256, 64,
                                                              (long)256 * 64, (long)NTOT * 64);
    dots_k<<<dim3(1152, 4), b256, 0, stream>>>(Wh, a_heads, f1h, f2h, 64);
    mh_stats<<<dim3(1152), b256, 0, stream>>>(sim, rinv, f1h, f2h, mxh, cih);
    mh_attn<<<dim3(72, 4, 6), b256, 0, stream>>>(sim, rinv, f1h, f2h, mxh, cih, Wh, acc1);
    mh_fin<<<dim3(NTOT * 256 / 1024), b256, 0, stream>>>(acc1, x1p, x2);
    // zero s partial accumulator (aliases x1p, now dead)
    zero_k<<<dim3(MU * 256 / 1024), b256, 0, stream>>>(acc2);
    // single GAT
    gemm_rm<false, false><<<dim3(72, 4, 1), b256, 0, stream>>>(x2, W_out, nullptr, Wh2, 256, 256, 0, 0);
    dots_k<<<dim3(1152, 1), b256, 0, stream>>>(Wh2, a_out, f1s, f2s, 256);
    s_stats<<<dim3(384), b256, 0, stream>>>(sim, rinv, f1s, f2s, mxs, cis);
    s_attn<<<dim3(48, 4, 6), b256, 0, stream>>>(sim, rinv, f1s, f2s, mxs, cis, Wh2, acc2);
    s_fin<<<dim3(MU * 256 / 1024), b256, 0, stream>>>(acc2, x2, x3);
    // feat_mlp rows TC.. -> out[0 : 1536*512]
    gemm_rm<false, true><<<dim3(24, 8, 1), b256, 0, stream>>>(x3, W_lin1, b_lin1, out, 256, 512, 0, 0);
    // bi-softmax outputs
    bi_partial<<<dim3(6, 12, 2), b256, 0, stream>>>(sim, rinv, pmax, psum);
    bi_combine<<<dim3(12), b256, 0, stream>>>(pmax, psum, fmx, fis);
    bi_norm<<<dim3(6, 12, 2), b256, 0, stream>>>(sim, rinv, fmx, fis, out + (long)MU * 512);
}

// Round 7
// 457.894 us; speedup vs baseline: 2.1942x; 1.2786x over previous
//
#include <hip/hip_runtime.h>
#include <hip/hip_bf16.h>
#include <math.h>

// Problem constants (from reference)
constexpr int NTOT = 4608;   // N_NODES
constexpr int TC   = 3072;   // TOTAL_CATS
constexpr int MU   = 1536;   // MAX_UNIFY
constexpr int NH   = 4;      // heads

// ---------------- workspace layout (float offsets) ----------------
constexpr long OFF_ADJ  = 0;                                  // N*N raw sim
constexpr long OFF_X1   = OFF_ADJ  + (long)NTOT*NTOT;         // N*256 (pre-relu)
constexpr long OFF_NAF  = OFF_X1   + (long)NTOT*256;          // N*64
constexpr long OFF_PART = OFF_NAF  + (long)NTOT*64;           // (unused)
constexpr long OFF_RINV = OFF_PART + 72*64;                   // N
constexpr long OFF_WH   = OFF_RINV + NTOT;                    // 4*N*64
constexpr long OFF_F1H  = OFF_WH   + (long)4*NTOT*64;         // 4*N
constexpr long OFF_F2H  = OFF_F1H  + (long)4*NTOT;
constexpr long OFF_MXH  = OFF_F2H  + (long)4*NTOT;            // (unused now)
constexpr long OFF_CIH  = OFF_MXH  + (long)4*NTOT;            // (unused now)
constexpr long OFF_X2   = OFF_CIH  + (long)4*NTOT;            // N*256
constexpr long OFF_WH2  = OFF_X2   + (long)NTOT*256;          // N*256 (acc1 before Wh2 exists)
constexpr long OFF_F1S  = OFF_WH2  + (long)NTOT*256;          // N
constexpr long OFF_F2S  = OFF_F1S  + NTOT;
constexpr long OFF_MXS  = OFF_F2S  + NTOT;                    // (unused now)
constexpr long OFF_CIS  = OFF_MXS  + NTOT;                    // (unused now)
constexpr long OFF_X3   = OFF_CIS  + NTOT;                    // 1536*256
constexpr long OFF_PMAX = OFF_X3   + (long)MU*256;            // 2*12*1536
constexpr long OFF_PSUM = OFF_PMAX + (long)2*12*MU;
constexpr long OFF_FMAX = OFF_PSUM + (long)2*12*MU;           // 2*1536
constexpr long OFF_FIS  = OFF_FMAX + (long)2*MU;
constexpr long OFF_L1   = OFF_FIS  + (long)2*MU;              // 4*N unnormalized row sums (mh)
constexpr long OFF_L2   = OFF_L1   + (long)4*NTOT;            // MU row sums (s)
// acc1 aliases OFF_WH2 (dead until after mh_fin); acc2 aliases OFF_X1 (x1p dead after mh_fin)

typedef __attribute__((ext_vector_type(8))) short bf16x8;
typedef __attribute__((ext_vector_type(4))) float floatx4;

__device__ __forceinline__ float lrelu(float x) { return (x >= 0.f) ? x : 0.2f * x; }
__device__ __forceinline__ float elu(float x)   { return (x > 0.f) ? x : expm1f(x); }
__device__ __forceinline__ unsigned short f2bf(float f) {
    unsigned u = __float_as_uint(f);
    u += 0x7FFFu + ((u >> 16) & 1u);           // round-to-nearest-even
    return (unsigned short)(u >> 16);
}

// ---------------- zero-fill (float4) ----------------
__global__ __launch_bounds__(256) void zero_k(float* __restrict__ p)
{
    long idx = ((long)blockIdx.x * 256 + threadIdx.x) * 4;
    *(float4*)(p + idx) = make_float4(0.f, 0.f, 0.f, 0.f);
}

// ---------------- generic tiled fp32 GEMM: C = A(NxK) @ B(KxM) [+bias] ----------------
template<bool RELU_A, bool BIAS>
__global__ __launch_bounds__(256) void gemm_rm(
    const float* __restrict__ A, const float* __restrict__ B,
    const float* __restrict__ bias, float* __restrict__ C,
    int K, int M, long strideBz, long strideCz)
{
    __shared__ float As[16][68];
    __shared__ float Bs[16][68];
    const float* Bz = B + (long)blockIdx.z * strideBz;
    float* Cz = C + (long)blockIdx.z * strideCz;
    int tid = threadIdx.x;
    int r0 = blockIdx.x * 64;
    int c0 = blockIdx.y * 64;
    int ty = tid >> 4, tx = tid & 15;
    float acc[4][4] = {};
    for (int k0 = 0; k0 < K; k0 += 16) {
        #pragma unroll
        for (int l = 0; l < 4; ++l) {
            int idx = l * 256 + tid;
            int row = idx >> 4, kk = idx & 15;
            float v = A[(long)(r0 + row) * K + k0 + kk];
            if (RELU_A) v = fmaxf(v, 0.f);
            As[kk][row] = v;
        }
        #pragma unroll
        for (int l = 0; l < 4; ++l) {
            int idx = l * 256 + tid;
            int kk = idx >> 6, col = idx & 63;
            Bs[kk][col] = Bz[(long)(k0 + kk) * M + c0 + col];
        }
        __syncthreads();
        #pragma unroll
        for (int kk = 0; kk < 16; ++kk) {
            float av[4], bv[4];
            #pragma unroll
            for (int i = 0; i < 4; ++i) av[i] = As[kk][ty * 4 + i];
            #pragma unroll
            for (int j = 0; j < 4; ++j) bv[j] = Bs[kk][tx * 4 + j];
            #pragma unroll
            for (int i = 0; i < 4; ++i)
                #pragma unroll
                for (int j = 0; j < 4; ++j) acc[i][j] += av[i] * bv[j];
        }
        __syncthreads();
    }
    #pragma unroll
    for (int i = 0; i < 4; ++i) {
        int r = r0 + ty * 4 + i;
        #pragma unroll
        for (int j = 0; j < 4; ++j) {
            int c = c0 + tx * 4 + j;
            float v = acc[i][j];
            if (BIAS) v += bias[c];
            Cz[(long)r * M + c] = v;
        }
    }
}

// ---------------- af = x1 @ W_adj + b_adj; naf = af / max(||af||, 1e-12) ----------------
__global__ __launch_bounds__(256) void af_naf(
    const float* __restrict__ x1, const float* __restrict__ W_adj,
    const float* __restrict__ b_adj, float* __restrict__ naf)
{
    __shared__ float rowbuf[4][256];
    int tid = threadIdx.x, w = tid >> 6, lane = tid & 63;
    int n = blockIdx.x * 4 + w;
    #pragma unroll
    for (int l = 0; l < 4; ++l) rowbuf[w][l * 64 + lane] = x1[(long)n * 256 + l * 64 + lane];
    __syncthreads();
    float acc = b_adj[lane];
    for (int k = 0; k < 256; ++k) acc += rowbuf[w][k] * W_adj[k * 64 + lane];
    float sq = acc * acc;
    #pragma unroll
    for (int off = 32; off >= 1; off >>= 1) sq += __shfl_xor(sq, off);
    float nrm = fmaxf(sqrtf(sq), 1e-12f);
    naf[(long)n * 64 + lane] = acc / nrm;
}

// ---------------- sim[n][m] = naf[n] . naf[m] (RAW, unscaled) ----------------
__global__ __launch_bounds__(256) void sim_k(
    const float* __restrict__ naf, float* __restrict__ sim)
{
    __shared__ float As[64][68];
    __shared__ float Bs[64][68];
    int tid = threadIdx.x;
    int n0 = blockIdx.x * 64, m0 = blockIdx.y * 64;
    #pragma unroll
    for (int l = 0; l < 16; ++l) {
        int idx = l * 256 + tid;
        int i = idx >> 6, k = idx & 63;
        As[i][k] = naf[(long)(n0 + i) * 64 + k];
        Bs[i][k] = naf[(long)(m0 + i) * 64 + k];
    }
    __syncthreads();
    int ty = tid >> 4, tx = tid & 15;
    float acc[4][4] = {};
    for (int k = 0; k < 64; ++k) {
        float av[4], bv[4];
        #pragma unroll
        for (int i = 0; i < 4; ++i) av[i] = As[ty * 4 + i][k];
        #pragma unroll
        for (int j = 0; j < 4; ++j) bv[j] = Bs[tx * 4 + j][k];
        #pragma unroll
        for (int i = 0; i < 4; ++i)
            #pragma unroll
            for (int j = 0; j < 4; ++j) acc[i][j] += av[i] * bv[j];
    }
    #pragma unroll
    for (int i = 0; i < 4; ++i) {
        int r = n0 + ty * 4 + i;
        #pragma unroll
        for (int j = 0; j < 4; ++j)
            sim[(long)r * NTOT + m0 + tx * 4 + j] = acc[i][j];
    }
}

// ---------------- rinv[n] = guard(1 / sum_m sim[n][m]), fp64-exact sum of rounded sims ----
__global__ __launch_bounds__(256) void rowsum_rinv(
    const float* __restrict__ sim, float* __restrict__ rinv)
{
    int tid = threadIdx.x, w = tid >> 6, lane = tid & 63;
    int n = blockIdx.x * 4 + w;
    const float* row = sim + (long)n * NTOT;
    double s = 0.0;
    for (int i = 0; i < 72; ++i) s += (double)row[i * 64 + lane];
    #pragma unroll
    for (int off = 32; off >= 1; off >>= 1) s += __shfl_xor(s, off);
    if (lane == 0) {
        float rs = (float)s;
        float r = 1.0f / rs;
        if (isinf(r)) r = 0.f;
        rinv[n] = r;
    }
}

// ---------------- f1/f2 dots ----------------
__global__ __launch_bounds__(256) void dots_k(
    const float* __restrict__ Wh, const float* __restrict__ a,
    float* __restrict__ f1, float* __restrict__ f2, int D)
{
    int tid = threadIdx.x, w = tid >> 6, lane = tid & 63;
    int n = blockIdx.x * 4 + w;
    int h = blockIdx.y;
    const float* row = Wh + ((long)h * NTOT + n) * D;
    const float* a1 = a + (long)h * 2 * D;
    const float* a2 = a1 + D;
    float p1 = 0.f, p2 = 0.f;
    for (int d = lane; d < D; d += 64) {
        float v = row[d];
        p1 += v * a1[d];
        p2 += v * a2[d];
    }
    #pragma unroll
    for (int off = 32; off >= 1; off >>= 1) { p1 += __shfl_xor(p1, off); p2 += __shfl_xor(p2, off); }
    if (lane == 0) { f1[(long)h * NTOT + n] = p1; f2[(long)h * NTOT + n] = p2; }
}

// ---------------- multihead att @ Wh via bf16 MFMA, UNNORMALIZED weights ----------------
// P = mask ? exp(lrelu(f1+f2)) : 0  (bounded scores -> no max-subtraction needed).
// Accumulates O' = sum P*Wh into accb (atomics) and l' = sum P into lbuf[h][n].
// grid (72 n-tiles, 4 heads, 6 m-chunks of 12 tiles).
__global__ __launch_bounds__(256) void mh_attn(
    const float* __restrict__ sim, const float* __restrict__ rinv,
    const float* __restrict__ f1, const float* __restrict__ f2,
    const float* __restrict__ Wh, float* __restrict__ accb, float* __restrict__ lbuf)
{
    __shared__ unsigned short Ps[64][72];   // P tile, row-major [n][m] bf16 (A operand)
    __shared__ unsigned short Ws[64][72];   // Wh tile TRANSPOSED [d][k] bf16 (B operand)
    __shared__ float rf1[64], rrv[64];
    int tid = threadIdx.x;
    int wave = tid >> 6, lane = tid & 63;
    int n0 = blockIdx.x * 64;
    int h = blockIdx.y, ch = blockIdx.z;
    const float* f1h = f1 + (long)h * NTOT;
    const float* f2h = f2 + (long)h * NTOT;
    const float* Whh = Wh + (long)h * NTOT * 64;
    if (tid < 64) { rf1[tid] = f1h[n0 + tid]; rrv[tid] = rinv[n0 + tid]; }
    __syncthreads();
    // staging roles: P: row pi, 16 cols from pj. Ws: col d=wd, 16 k's from wk.
    int pi = tid >> 2, pj = (tid & 3) * 16;
    int wd = tid & 63, wk = (tid >> 6) * 16;
    float r1 = rf1[pi], rv = rrv[pi];
    float lsum = 0.f;
    floatx4 acc[4] = {};
    for (int mt = ch * 12; mt < ch * 12 + 12; ++mt) {
        int m0 = mt * 64;
        __syncthreads();      // prior MFMA reads done
        #pragma unroll
        for (int q = 0; q < 4; ++q) {
            int mc = pj + q * 4;
            float4 sv = *(const float4*)(sim + (long)(n0 + pi) * NTOT + m0 + mc);
            float4 fv = *(const float4*)(f2h + m0 + mc);
            float p0 = ((sv.x * rv) > 0.f) ? __expf(lrelu(r1 + fv.x)) : 0.f;
            float p1 = ((sv.y * rv) > 0.f) ? __expf(lrelu(r1 + fv.y)) : 0.f;
            float p2 = ((sv.z * rv) > 0.f) ? __expf(lrelu(r1 + fv.z)) : 0.f;
            float p3 = ((sv.w * rv) > 0.f) ? __expf(lrelu(r1 + fv.w)) : 0.f;
            lsum += (p0 + p1) + (p2 + p3);
            ushort4 pv;
            pv.x = f2bf(p0); pv.y = f2bf(p1); pv.z = f2bf(p2); pv.w = f2bf(p3);
            *(ushort4*)&Ps[pi][mc] = pv;
        }
        #pragma unroll
        for (int q = 0; q < 4; ++q) {
            int k = wk + q * 4;
            ushort4 wv;   // coalesced across lanes (wd consecutive)
            wv.x = f2bf(Whh[(long)(m0 + k + 0) * 64 + wd]);
            wv.y = f2bf(Whh[(long)(m0 + k + 1) * 64 + wd]);
            wv.z = f2bf(Whh[(long)(m0 + k + 2) * 64 + wd]);
            wv.w = f2bf(Whh[(long)(m0 + k + 3) * 64 + wd]);
            *(ushort4*)&Ws[wd][k] = wv;
        }
        __syncthreads();
        #pragma unroll
        for (int ks = 0; ks < 2; ++ks) {
            bf16x8 af = *(bf16x8*)&Ps[16 * wave + (lane & 15)][ks * 32 + (lane >> 4) * 8];
            #pragma unroll
            for (int dt = 0; dt < 4; ++dt) {
                bf16x8 bfr = *(bf16x8*)&Ws[16 * dt + (lane & 15)][ks * 32 + (lane >> 4) * 8];
                acc[dt] = __builtin_amdgcn_mfma_f32_16x16x32_bf16(af, bfr, acc[dt], 0, 0, 0);
            }
        }
    }
    // per-row l' partial: 4 threads per row (tid = 4*pi .. 4*pi+3, same wave)
    lsum += __shfl_xor(lsum, 1);
    lsum += __shfl_xor(lsum, 2);
    if ((tid & 3) == 0) atomicAdd(lbuf + (long)h * NTOT + n0 + pi, lsum);
    // C/D layout: col = lane&15, row = (lane>>4)*4 + reg   [m89-verified]
    int crow = n0 + 16 * wave + (lane >> 4) * 4;
    int ccol = h * 64 + (lane & 15);
    #pragma unroll
    for (int dt = 0; dt < 4; ++dt)
        #pragma unroll
        for (int r = 0; r < 4; ++r)
            atomicAdd(accb + (long)(crow + r) * 256 + ccol + dt * 16, acc[dt][r]);
}

// ---------------- mh epilogue: x2 = elu(acc / l') + relu(x1) ----------------
__global__ __launch_bounds__(256) void mh_fin(
    const float* __restrict__ accb, const float* __restrict__ lbuf,
    const float* __restrict__ x1, float* __restrict__ x2)
{
    long idx = ((long)blockIdx.x * 256 + threadIdx.x) * 4;
    long r = idx >> 8;
    int h = (int)((idx & 255) >> 6);
    float l = lbuf[(long)h * NTOT + r];
    float inv = (l > 0.f) ? 1.0f / l : 0.f;
    float4 a = *(const float4*)(accb + idx);
    float4 xv = *(const float4*)(x1 + idx);
    float4 o;
    o.x = elu(a.x * inv) + fmaxf(xv.x, 0.f);
    o.y = elu(a.y * inv) + fmaxf(xv.y, 0.f);
    o.z = elu(a.z * inv) + fmaxf(xv.z, 0.f);
    o.w = elu(a.w * inv) + fmaxf(xv.w, 0.f);
    *(float4*)(x2 + idx) = o;
}

// ---------------- single-head att @ Wh2 via bf16 MFMA (rows >= TC), unnormalized ----------------
// grid (48 row-tiles of 32, 4 col-tiles of 64, 6 m-chunks).
__global__ __launch_bounds__(256) void s_attn(
    const float* __restrict__ sim, const float* __restrict__ rinv,
    const float* __restrict__ f1, const float* __restrict__ f2,
    const float* __restrict__ Wh2, float* __restrict__ accb, float* __restrict__ lbuf)
{
    __shared__ unsigned short Ps[32][72];   // P tile [n][m] bf16
    __shared__ unsigned short Ws[64][72];   // Wh2 tile transposed [d][k] bf16
    __shared__ float rf1[32], rrv[32];
    int tid = threadIdx.x;
    int wave = tid >> 6, lane = tid & 63;
    int lr0 = blockIdx.x * 32;
    int c0 = blockIdx.y * 64;
    int ch = blockIdx.z;
    int n0 = TC + lr0;
    if (tid < 32) { rf1[tid] = f1[n0 + tid]; rrv[tid] = rinv[n0 + tid]; }
    __syncthreads();
    int pi = tid >> 3, pj = (tid & 7) * 8;      // P: row 0..31, 8 cols
    int wd = tid & 63, wk = (tid >> 6) * 16;    // Ws: d, 16 k's
    float r1 = rf1[pi], rv = rrv[pi];
    int rt = wave & 1;                           // row-tile (16 rows)
    int dt0 = (wave >> 1) * 2;                   // first of 2 d-tiles
    float lsum = 0.f;
    floatx4 acc[2] = {};
    for (int mt = ch * 12; mt < ch * 12 + 12; ++mt) {
        int m0 = mt * 64;
        __syncthreads();
        #pragma unroll
        for (int q = 0; q < 2; ++q) {
            int mc = pj + q * 4;
            float4 sv = *(const float4*)(sim + (long)(n0 + pi) * NTOT + m0 + mc);
            float4 fv = *(const float4*)(f2 + m0 + mc);
            float p0 = ((sv.x * rv) > 0.f) ? __expf(lrelu(r1 + fv.x)) : 0.f;
            float p1 = ((sv.y * rv) > 0.f) ? __expf(lrelu(r1 + fv.y)) : 0.f;
            float p2 = ((sv.z * rv) > 0.f) ? __expf(lrelu(r1 + fv.z)) : 0.f;
            float p3 = ((sv.w * rv) > 0.f) ? __expf(lrelu(r1 + fv.w)) : 0.f;
            lsum += (p0 + p1) + (p2 + p3);
            ushort4 pv;
            pv.x = f2bf(p0); pv.y = f2bf(p1); pv.z = f2bf(p2); pv.w = f2bf(p3);
            *(ushort4*)&Ps[pi][mc] = pv;
        }
        #pragma unroll
        for (int q = 0; q < 4; ++q) {
            int k = wk + q * 4;
            ushort4 wv;
            wv.x = f2bf(Wh2[(long)(m0 + k + 0) * 256 + c0 + wd]);
            wv.y = f2bf(Wh2[(long)(m0 + k + 1) * 256 + c0 + wd]);
            wv.z = f2bf(Wh2[(long)(m0 + k + 2) * 256 + c0 + wd]);
            wv.w = f2bf(Wh2[(long)(m0 + k + 3) * 256 + c0 + wd]);
            *(ushort4*)&Ws[wd][k] = wv;
        }
        __syncthreads();
        #pragma unroll
        for (int ks = 0; ks < 2; ++ks) {
            bf16x8 af = *(bf16x8*)&Ps[16 * rt + (lane & 15)][ks * 32 + (lane >> 4) * 8];
            #pragma unroll
            for (int t = 0; t < 2; ++t) {
                bf16x8 bfr = *(bf16x8*)&Ws[16 * (dt0 + t) + (lane & 15)][ks * 32 + (lane >> 4) * 8];
                acc[t] = __builtin_amdgcn_mfma_f32_16x16x32_bf16(af, bfr, acc[t], 0, 0, 0);
            }
        }
    }
    // per-row l' partial: 8 threads per row; only col-tile 0 contributes (avoid 4x overcount)
    lsum += __shfl_xor(lsum, 1);
    lsum += __shfl_xor(lsum, 2);
    lsum += __shfl_xor(lsum, 4);
    if (blockIdx.y == 0 && (tid & 7) == 0) atomicAdd(lbuf + lr0 + pi, lsum);
    int crow = lr0 + 16 * rt + (lane >> 4) * 4;
    int ccol = c0 + (lane & 15);
    #pragma unroll
    for (int t = 0; t < 2; ++t)
        #pragma unroll
        for (int r = 0; r < 4; ++r)
            atomicAdd(accb + (long)(crow + r) * 256 + ccol + (dt0 + t) * 16, acc[t][r]);
}

// ---------------- s epilogue: x3 = elu(acc / l' + x2[TC..]) ----------------
__global__ __launch_bounds__(256) void s_fin(
    const float* __restrict__ accb, const float* __restrict__ lbuf,
    const float* __restrict__ x2, float* __restrict__ x3)
{
    long idx = ((long)blockIdx.x * 256 + threadIdx.x) * 4;
    long r = idx >> 8;
    float l = lbuf[r];
    float inv = (l > 0.f) ? 1.0f / l : 0.f;
    float4 a = *(const float4*)(accb + idx);
    float4 xv = *(const float4*)(x2 + (long)TC * 256 + idx);
    float4 o;
    o.x = elu(a.x * inv + xv.x);
    o.y = elu(a.y * inv + xv.y);
    o.z = elu(a.z * inv + xv.z);
    o.w = elu(a.w * inv + xv.w);
    *(float4*)(x3 + idx) = o;
}

// ---------------- bi-softmax phase A ----------------
__global__ __launch_bounds__(256) void bi_partial(
    const float* __restrict__ sim, const float* __restrict__ rinv,
    float* __restrict__ pmax, float* __restrict__ psum)
{
    int c = blockIdx.x * 256 + threadIdx.x;
    int ch = blockIdx.y;
    int ds = blockIdx.z;
    float m = -3.0e38f, s = 0.f;
    int rbase = ds * MU + ch * 128;
    for (int r = 0; r < 128; ++r) {
        float a = sim[(long)(rbase + r) * NTOT + TC + c] * rinv[rbase + r];
        float v = a * 20.0f;
        if (v <= m) s += expf(v - m);
        else { s = s * expf(m - v) + 1.f; m = v; }
    }
    pmax[((long)ds * 12 + ch) * MU + c] = m;
    psum[((long)ds * 12 + ch) * MU + c] = s;
}

// ---------------- bi-softmax phase B ----------------
__global__ __launch_bounds__(256) void bi_combine(
    const float* __restrict__ pmax, const float* __restrict__ psum,
    float* __restrict__ fmax, float* __restrict__ fis)
{
    int b = blockIdx.x;
    int ds = b / 6, ct = b % 6;
    int c = ct * 256 + threadIdx.x;
    float m = -3.0e38f;
    for (int ch = 0; ch < 12; ++ch) m = fmaxf(m, pmax[((long)ds * 12 + ch) * MU + c]);
    float s = 0.f;
    for (int ch = 0; ch < 12; ++ch)
        s += psum[((long)ds * 12 + ch) * MU + c] * expf(pmax[((long)ds * 12 + ch) * MU + c] - m);
    fmax[ds * MU + c] = m;
    fis[ds * MU + c] = 1.0f / s;
}

// ---------------- bi-softmax phase C ----------------
__global__ __launch_bounds__(256) void bi_norm(
    const float* __restrict__ sim, const float* __restrict__ rinv,
    const float* __restrict__ fmax, const float* __restrict__ fis,
    float* __restrict__ outbg)
{
    int c = blockIdx.x * 256 + threadIdx.x;
    int ch = blockIdx.y;
    int ds = blockIdx.z;
    float m = fmax[ds * MU + c], inv = fis[ds * MU + c];
    long obase = (long)ds * MU * MU;
    int rbase = ch * 128;
    for (int r = 0; r < 128; ++r) {
        int row = ds * MU + rbase + r;
        float a = sim[(long)row * NTOT + TC + c] * rinv[row];
        float v = a * 20.0f;
        outbg[obase + (long)(rbase + r) * MU + c] = expf(v - m) * inv;
    }
}

// ---------------- launch ----------------
extern "C" void kernel_launch(void* const* d_in, const int* in_sizes, int n_in,
                              void* d_out, int out_size, void* d_ws, size_t ws_size,
                              hipStream_t stream)
{
    const float* x        = (const float*)d_in[0];
    const float* W_before = (const float*)d_in[1];
    const float* b_before = (const float*)d_in[2];
    const float* W_adj    = (const float*)d_in[3];
    const float* b_adj    = (const float*)d_in[4];
    const float* W_heads  = (const float*)d_in[5];
    const float* a_heads  = (const float*)d_in[6];
    const float* W_out    = (const float*)d_in[7];
    const float* a_out    = (const float*)d_in[8];
    const float* W_lin1   = (const float*)d_in[9];
    const float* b_lin1   = (const float*)d_in[10];
    float* out = (float*)d_out;
    float* ws  = (float*)d_ws;

    float* sim  = ws + OFF_ADJ;
    float* x1p  = ws + OFF_X1;
    float* naf  = ws + OFF_NAF;
    float* rinv = ws + OFF_RINV;
    float* Wh   = ws + OFF_WH;
    float* f1h  = ws + OFF_F1H;
    float* f2h  = ws + OFF_F2H;
    float* x2   = ws + OFF_X2;
    float* Wh2  = ws + OFF_WH2;
    float* f1s  = ws + OFF_F1S;
    float* f2s  = ws + OFF_F2S;
    float* x3   = ws + OFF_X3;
    float* pmax = ws + OFF_PMAX;
    float* psum = ws + OFF_PSUM;
    float* fmx  = ws + OFF_FMAX;
    float* fis  = ws + OFF_FIS;
    float* l1   = ws + OFF_L1;
    float* l2   = ws + OFF_L2;
    float* acc1 = ws + OFF_WH2;   // alias: dead until Wh2 gemm (after mh_fin)
    float* acc2 = ws + OFF_X1;    // alias: x1p dead after mh_fin

    dim3 b256(256);

    // zero mh partial accumulator (aliases Wh2 region) and l1+l2 row-sum buffers
    zero_k<<<dim3(NTOT * 256 / 1024), b256, 0, stream>>>(acc1);
    zero_k<<<dim3(20), b256, 0, stream>>>(l1);   // covers l1 (4*N) + l2 (MU) + pad
    // x1_pre = x @ W_before + b
    gemm_rm<false, true><<<dim3(72, 4, 1), b256, 0, stream>>>(x, W_before, b_before, x1p, 512, 256, 0, 0);
    // adjacency features
    af_naf<<<dim3(1152), b256, 0, stream>>>(x1p, W_adj, b_adj, naf);
    sim_k<<<dim3(72, 72), b256, 0, stream>>>(naf, sim);
    rowsum_rinv<<<dim3(1152), b256, 0, stream>>>(sim, rinv);
    // multihead: Wh[h] = relu(x1) @ W_heads[h]
    gemm_rm<true, false><<<dim3(72, 1, 4), b256, 0, stream>>>(x1p, W_heads, nullptr, Wh, 256, 64,
                                                              (long)256 * 64, (long)NTOT * 64);
    dots_k<<<dim3(1152, 4), b256, 0, stream>>>(Wh, a_heads, f1h, f2h, 64);
    mh_attn<<<dim3(72, 4, 6), b256, 0, stream>>>(sim, rinv, f1h, f2h, Wh, acc1, l1);
    mh_fin<<<dim3(NTOT * 256 / 1024), b256, 0, stream>>>(acc1, l1, x1p, x2);
    // zero s partial accumulator (aliases x1p, now dead)
    zero_k<<<dim3(MU * 256 / 1024), b256, 0, stream>>>(acc2);
    // single GAT
    gemm_rm<false, false><<<dim3(72, 4, 1), b256, 0, stream>>>(x2, W_out, nullptr, Wh2, 256, 256, 0, 0);
    dots_k<<<dim3(1152, 1), b256, 0, stream>>>(Wh2, a_out, f1s, f2s, 256);
    s_attn<<<dim3(48, 4, 6), b256, 0, stream>>>(sim, rinv, f1s, f2s, Wh2, acc2, l2);
    s_fin<<<dim3(MU * 256 / 1024), b256, 0, stream>>>(acc2, l2, x2, x3);
    // feat_mlp rows TC.. -> out[0 : 1536*512]
    gemm_rm<false, true><<<dim3(24, 8, 1), b256, 0, stream>>>(x3, W_lin1, b_lin1, out, 256, 512, 0, 0);
    // bi-softmax outputs
    bi_partial<<<dim3(6, 12, 2), b256, 0, stream>>>(sim, rinv, pmax, psum);
    bi_combine<<<dim3(12), b256, 0, stream>>>(pmax, psum, fmx, fis);
    bi_norm<<<dim3(6, 12, 2), b256, 0, stream>>>(sim, rinv, fmx, fis, out + (long)MU * 512);
}